// Round 2
// baseline (2142.709 us; speedup 1.0000x reference)
//
#include <hip/hip_runtime.h>
#include <hip/hip_bf16.h>

#define D 128
#define AGG_BLOCKS 512

// ---------------------------------------------------------------- degree + count
__global__ void deg_cnt_kernel(const int* __restrict__ dst_idx,
                               const float* __restrict__ w,
                               float* __restrict__ deg, int* __restrict__ cnt, int E, int N) {
    int e = blockIdx.x * blockDim.x + threadIdx.x;
    int stride = gridDim.x * blockDim.x;
    for (; e < E; e += stride) {
        int d = dst_idx[e];
        if ((unsigned)d < (unsigned)N) {
            atomicAdd(&deg[d], w[e]);
            atomicAdd(&cnt[d], 1);
        }
    }
}

// ---------------------------------------------------------------- dinv = deg>0 ? rsqrt(deg) : 0
__global__ void dinv_kernel(float* __restrict__ deg, int n) {
    int i = blockIdx.x * blockDim.x + threadIdx.x;
    int stride = gridDim.x * blockDim.x;
    for (; i < n; i += stride) {
        float d = deg[i];
        deg[i] = (d > 0.f) ? rsqrtf(d) : 0.f;
    }
}

// ---------------------------------------------------------------- exclusive scan (single block)
__global__ void scan_kernel(const int* __restrict__ cnt, int* __restrict__ row_ptr, int n) {
    __shared__ int s[256];
    int t = threadIdx.x;
    int chunk = (n + 255) / 256;
    int lo = t * chunk;
    int hi = lo + chunk; if (hi > n) hi = n;
    int sum = 0;
    for (int i = lo; i < hi; i++) sum += cnt[i];
    s[t] = sum;
    __syncthreads();
    for (int off = 1; off < 256; off <<= 1) {
        int v = (t >= off) ? s[t - off] : 0;
        __syncthreads();
        s[t] += v;
        __syncthreads();
    }
    int run = (t == 0) ? 0 : s[t - 1];
    for (int i = lo; i < hi; i++) { row_ptr[i] = run; run += cnt[i]; }
    if (t == 255) row_ptr[n] = run;
}

// ---------------------------------------------------------------- fill CSR (counting sort by dst)
__global__ void fill_csr_kernel(const int* __restrict__ idx,
                                const float* __restrict__ w,
                                const float* __restrict__ dinv,
                                int* __restrict__ cursor,
                                int* __restrict__ csr_src, float* __restrict__ csr_w,
                                int E, int N) {
    int e = blockIdx.x * blockDim.x + threadIdx.x;
    int stride = gridDim.x * blockDim.x;
    for (; e < E; e += stride) {
        int s = idx[e];
        int d = idx[(size_t)E + e];
        if ((unsigned)s >= (unsigned)N || (unsigned)d >= (unsigned)N) continue;
        float nrm = dinv[s] * w[e] * dinv[d];
        int p = atomicAdd(&cursor[d], 1);
        csr_src[p] = s;
        csr_w[p]   = nrm;
    }
}

// ---------------------------------------------------------------- GEMM: out = H @ Wl   [n,128]x[128,128]
__global__ void gemm128_kernel(const float* __restrict__ H, const float* __restrict__ Wl,
                               float* __restrict__ out, int n) {
    __shared__ float Ws[D * D];      // 64 KiB (gfx950 has 160 KiB LDS/CU)
    __shared__ float hs[8][D];       // 4 KiB
    int t = threadIdx.x;
    for (int i = t; i < D * D / 4; i += 256)
        ((float4*)Ws)[i] = ((const float4*)Wl)[i];
    __syncthreads();

    int r = t >> 5;    // 0..7 row within 8-row strip
    int cg = t & 31;   // column group of 4
    for (int base = blockIdx.x * 8; base < n; base += gridDim.x * 8) {
        int rows = n - base; if (rows > 8) rows = 8;
        if (r < rows)
            *(float4*)&hs[r][cg * 4] = *(const float4*)(H + (size_t)(base + r) * D + cg * 4);
        __syncthreads();
        if (r < rows) {
            float4 acc = make_float4(0.f, 0.f, 0.f, 0.f);
            #pragma unroll 8
            for (int k = 0; k < D; k++) {
                float hv = hs[r][k];
                float4 wv = *(const float4*)&Ws[k * D + cg * 4];
                acc.x += hv * wv.x; acc.y += hv * wv.y;
                acc.z += hv * wv.z; acc.w += hv * wv.w;
            }
            *(float4*)(out + (size_t)(base + r) * D + cg * 4) = acc;
        }
        __syncthreads();
    }
}

// ---------------------------------------------------------------- pull aggregation + bias + residual + col-stats
// one wave (64 lanes) per dst node; lane owns columns (2l, 2l+1)
__global__ void agg_kernel(const float* __restrict__ xl,
                           const int* __restrict__ row_ptr,
                           const int* __restrict__ csr_src,
                           const float* __restrict__ csr_w,
                           const float* __restrict__ bvec,
                           float* __restrict__ hr,        // out (== h_last buffer)
                           float* __restrict__ partial,   // [gridDim.x][256]
                           int n, int has_res) {
    int wave = threadIdx.x >> 6;
    int lane = threadIdx.x & 63;
    int gwave = blockIdx.x * 4 + wave;
    int nwaves = gridDim.x * 4;

    float b0 = bvec[lane * 2], b1 = bvec[lane * 2 + 1];
    float s0 = 0.f, s1 = 0.f, q0 = 0.f, q1 = 0.f;

    for (int i = gwave; i < n; i += nwaves) {
        int beg = row_ptr[i], end = row_ptr[i + 1];
        float a0 = 0.f, a1 = 0.f;
        for (int e = beg; e < end; e++) {
            int s = csr_src[e];
            float wv = csr_w[e];
            float2 v = *(const float2*)(xl + (size_t)s * D + lane * 2);
            a0 += wv * v.x;
            a1 += wv * v.y;
        }
        a0 += b0; a1 += b1;
        if (has_res) {
            float2 rr = *(const float2*)(hr + (size_t)i * D + lane * 2);
            a0 += rr.x; a1 += rr.y;
        }
        *(float2*)(hr + (size_t)i * D + lane * 2) = make_float2(a0, a1);
        s0 += a0; s1 += a1;
        q0 += a0 * a0; q1 += a1 * a1;
    }

    __shared__ float redS[4][D];
    __shared__ float redQ[4][D];
    redS[wave][lane * 2] = s0; redS[wave][lane * 2 + 1] = s1;
    redQ[wave][lane * 2] = q0; redQ[wave][lane * 2 + 1] = q1;
    __syncthreads();
    int t = threadIdx.x;
    if (t < 128) {
        partial[(size_t)blockIdx.x * 256 + t] =
            redS[0][t] + redS[1][t] + redS[2][t] + redS[3][t];
    } else {
        int c = t - 128;
        partial[(size_t)blockIdx.x * 256 + t] =
            redQ[0][c] + redQ[1][c] + redQ[2][c] + redQ[3][c];
    }
}

// ---------------------------------------------------------------- finalize stats -> per-col scale/shift
__global__ void finalize_kernel(const float* __restrict__ partial, int nblk,
                                const float* __restrict__ gamma_l,
                                const float* __restrict__ beta_l,
                                float* __restrict__ AB, float n_inv) {
    int t = threadIdx.x; // 256
    float acc = 0.f;
    for (int b = 0; b < nblk; b++) acc += partial[(size_t)b * 256 + t];
    __shared__ float L[256];
    L[t] = acc;
    __syncthreads();
    if (t < 128) {
        float mean = L[t] * n_inv;
        float var  = L[t + 128] * n_inv - mean * mean;
        var = fmaxf(var, 0.f);
        float rstd = rsqrtf(var + 1e-5f);
        float A = rstd * gamma_l[t];
        float B = beta_l[t] - mean * A;
        AB[t] = A;
        AB[128 + t] = B;
    }
}

// ---------------------------------------------------------------- normalize + relu
__global__ void norm_relu_kernel(const float* __restrict__ hr, const float* __restrict__ AB,
                                 float* __restrict__ hout, int total4) {
    int idx = blockIdx.x * blockDim.x + threadIdx.x;
    int stride = gridDim.x * blockDim.x;
    for (; idx < total4; idx += stride) {
        int c4 = (idx & 31) * 4;
        float4 v = ((const float4*)hr)[idx];
        float4 A = *(const float4*)(AB + c4);
        float4 B = *(const float4*)(AB + 128 + c4);
        v.x = fmaxf(fmaf(v.x, A.x, B.x), 0.f);
        v.y = fmaxf(fmaf(v.y, A.y, B.y), 0.f);
        v.z = fmaxf(fmaf(v.z, A.z, B.z), 0.f);
        v.w = fmaxf(fmaf(v.w, A.w, B.w), 0.f);
        ((float4*)hout)[idx] = v;
    }
}

// ================================================================ launch
extern "C" void kernel_launch(void* const* d_in, const int* in_sizes, int n_in,
                              void* d_out, int out_size, void* d_ws, size_t ws_size,
                              hipStream_t stream) {
    const float* x    = (const float*)d_in[0];
    const int*   eidx = (const int*)d_in[1];     // int32 per harness contract
    const float* ew   = (const float*)d_in[2];
    const float* W    = (const float*)d_in[3];
    const float* b    = (const float*)d_in[4];
    const float* gmm  = (const float*)d_in[5];
    const float* bet  = (const float*)d_in[6];

    const int N = in_sizes[0] / D;
    const int E = in_sizes[2];
    const int L = in_sizes[4] / D;

    // ---- carve workspace
    size_t off = 0;
    auto carve = [&](size_t bytes) -> void* {
        void* p = (char*)d_ws + off;
        off += (bytes + 255) & ~(size_t)255;
        return p;
    };
    float* deg     = (float*)carve((size_t)N * 4);        // becomes dinv
    int*   cnt     = (int*)  carve((size_t)N * 4);
    int*   row_ptr = (int*)  carve((size_t)(N + 1) * 4);
    int*   cursor  = (int*)  carve((size_t)N * 4);
    int*   csr_src = (int*)  carve((size_t)E * 4);
    float* csr_w   = (float*)carve((size_t)E * 4);
    float* xl      = (float*)carve((size_t)N * D * 4);
    float* hr      = (float*)carve((size_t)N * D * 4);
    float* partial = (float*)carve((size_t)AGG_BLOCKS * 256 * 4);
    float* AB      = (float*)carve(256 * 4);
    if (off > ws_size) return; // workspace too small — bail rather than corrupt

    float* hout = (float*)d_out;

    // ---- build normalization + CSR
    hipMemsetAsync(deg, 0, (size_t)N * 4, stream);
    hipMemsetAsync(cnt, 0, (size_t)N * 4, stream);
    deg_cnt_kernel<<<2048, 256, 0, stream>>>(eidx + E, ew, deg, cnt, E, N);
    dinv_kernel<<<256, 256, 0, stream>>>(deg, N);
    scan_kernel<<<1, 256, 0, stream>>>(cnt, row_ptr, N);
    hipMemcpyAsync(cursor, row_ptr, (size_t)N * 4, hipMemcpyDeviceToDevice, stream);
    fill_csr_kernel<<<2048, 256, 0, stream>>>(eidx, ew, deg, cursor, csr_src, csr_w, E, N);

    // ---- layers
    const float n_inv = 1.f / (float)N;
    const float* Hin = x;
    for (int l = 0; l < L; l++) {
        gemm128_kernel<<<1024, 256, 0, stream>>>(Hin, W + (size_t)l * D * D, xl, N);
        agg_kernel<<<AGG_BLOCKS, 256, 0, stream>>>(xl, row_ptr, csr_src, csr_w,
                                                   b + (size_t)l * D, hr, partial,
                                                   N, l > 0 ? 1 : 0);
        finalize_kernel<<<1, 256, 0, stream>>>(partial, AGG_BLOCKS,
                                               gmm + (size_t)l * D, bet + (size_t)l * D,
                                               AB, n_inv);
        norm_relu_kernel<<<1024, 256, 0, stream>>>(hr, AB, hout, N * (D / 4));
        Hin = hout;
    }
}

// Round 3
// 966.442 us; speedup vs baseline: 2.2171x; 2.2171x over previous
//
#include <hip/hip_runtime.h>
#include <hip/hip_bf16.h>

#define D 128
#define AGG_BLOCKS 2048

// ---------------------------------------------------------------- degree + count
__global__ void deg_cnt_kernel(const int* __restrict__ dst_idx,
                               const float* __restrict__ w,
                               float* __restrict__ deg, int* __restrict__ cnt, int E, int N) {
    int e = blockIdx.x * blockDim.x + threadIdx.x;
    int stride = gridDim.x * blockDim.x;
    for (; e < E; e += stride) {
        int d = dst_idx[e];
        if ((unsigned)d < (unsigned)N) {
            atomicAdd(&deg[d], w[e]);
            atomicAdd(&cnt[d], 1);
        }
    }
}

// ---------------------------------------------------------------- dinv = deg>0 ? rsqrt(deg) : 0
__global__ void dinv_kernel(float* __restrict__ deg, int n) {
    int i = blockIdx.x * blockDim.x + threadIdx.x;
    int stride = gridDim.x * blockDim.x;
    for (; i < n; i += stride) {
        float d = deg[i];
        deg[i] = (d > 0.f) ? rsqrtf(d) : 0.f;
    }
}

// ---------------------------------------------------------------- exclusive scan (single block)
__global__ void scan_kernel(const int* __restrict__ cnt, int* __restrict__ row_ptr, int n) {
    __shared__ int s[256];
    int t = threadIdx.x;
    int chunk = (n + 255) / 256;
    int lo = t * chunk;
    int hi = lo + chunk; if (hi > n) hi = n;
    int sum = 0;
    for (int i = lo; i < hi; i++) sum += cnt[i];
    s[t] = sum;
    __syncthreads();
    for (int off = 1; off < 256; off <<= 1) {
        int v = (t >= off) ? s[t - off] : 0;
        __syncthreads();
        s[t] += v;
        __syncthreads();
    }
    int run = (t == 0) ? 0 : s[t - 1];
    for (int i = lo; i < hi; i++) { row_ptr[i] = run; run += cnt[i]; }
    if (t == 255) row_ptr[n] = run;
}

// ---------------------------------------------------------------- fill CSR (counting sort by dst)
__global__ void fill_csr_kernel(const int* __restrict__ idx,
                                const float* __restrict__ w,
                                const float* __restrict__ dinv,
                                int* __restrict__ cursor,
                                int* __restrict__ csr_src, float* __restrict__ csr_w,
                                int E, int N) {
    int e = blockIdx.x * blockDim.x + threadIdx.x;
    int stride = gridDim.x * blockDim.x;
    for (; e < E; e += stride) {
        int s = idx[e];
        int d = idx[(size_t)E + e];
        if ((unsigned)s >= (unsigned)N || (unsigned)d >= (unsigned)N) continue;
        float nrm = dinv[s] * w[e] * dinv[d];
        int p = atomicAdd(&cursor[d], 1);
        csr_src[p] = s;
        csr_w[p]   = nrm;
    }
}

// ---------------------------------------------------------------- GEMM: out = H @ Wl   [n,128]x[128,128]
// 16 rows per block-iter, each thread computes 2 rows x 4 cols.
__global__ void gemm128_kernel(const float* __restrict__ H, const float* __restrict__ Wl,
                               float* __restrict__ out, int n) {
    __shared__ float Ws[D * D];      // 64 KiB
    __shared__ float hs[16][D];      // 8 KiB
    int t = threadIdx.x;
    for (int i = t; i < D * D / 4; i += 256)
        ((float4*)Ws)[i] = ((const float4*)Wl)[i];
    __syncthreads();

    int r  = t >> 5;   // 0..7 -> rows r and r+8
    int cg = t & 31;   // column group of 4
    for (int base = blockIdx.x * 16; base < n; base += gridDim.x * 16) {
        int rows = n - base; if (rows > 16) rows = 16;
        for (int i = t; i < 16 * 32; i += 256) {
            int rr = i >> 5, cc = i & 31;
            if (rr < rows)
                ((float4*)hs)[i] = *(const float4*)(H + (size_t)(base + rr) * D + cc * 4);
        }
        __syncthreads();
        float4 acc0 = make_float4(0.f, 0.f, 0.f, 0.f);
        float4 acc1 = make_float4(0.f, 0.f, 0.f, 0.f);
        #pragma unroll 8
        for (int k = 0; k < D; k++) {
            float h0 = hs[r][k];
            float h1 = hs[r + 8][k];
            float4 wv = *(const float4*)&Ws[k * D + cg * 4];
            acc0.x += h0 * wv.x; acc0.y += h0 * wv.y;
            acc0.z += h0 * wv.z; acc0.w += h0 * wv.w;
            acc1.x += h1 * wv.x; acc1.y += h1 * wv.y;
            acc1.z += h1 * wv.z; acc1.w += h1 * wv.w;
        }
        if (r < rows)
            *(float4*)(out + (size_t)(base + r) * D + cg * 4) = acc0;
        if (r + 8 < rows)
            *(float4*)(out + (size_t)(base + r + 8) * D + cg * 4) = acc1;
        __syncthreads();
    }
}

// ---------------------------------------------------------------- pull aggregation + bias + residual + col-stats
// one wave (64 lanes) per dst node; lane owns columns (2l, 2l+1); 4x-unrolled edge loop for MLP
__global__ void agg_kernel(const float* __restrict__ xl,
                           const int* __restrict__ row_ptr,
                           const int* __restrict__ csr_src,
                           const float* __restrict__ csr_w,
                           const float* __restrict__ bvec,
                           float* __restrict__ hr,        // out (== h_last buffer)
                           float* __restrict__ stats,     // [256]: sum | sumsq (atomic)
                           int n, int has_res) {
    int wave = threadIdx.x >> 6;
    int lane = threadIdx.x & 63;
    int gwave = blockIdx.x * 4 + wave;
    int nwaves = gridDim.x * 4;

    float bb0 = bvec[lane * 2], bb1 = bvec[lane * 2 + 1];
    float s0 = 0.f, s1 = 0.f, q0 = 0.f, q1 = 0.f;

    for (int i = gwave; i < n; i += nwaves) {
        int beg = row_ptr[i], end = row_ptr[i + 1];
        float p0 = 0.f, p1 = 0.f, p2 = 0.f, p3 = 0.f;
        float p4 = 0.f, p5 = 0.f, p6 = 0.f, p7 = 0.f;
        int e = beg;
        int e4 = beg + ((end - beg) & ~3);
        for (; e < e4; e += 4) {
            int   i0 = csr_src[e],     i1 = csr_src[e + 1];
            int   i2 = csr_src[e + 2], i3 = csr_src[e + 3];
            float w0 = csr_w[e],       w1 = csr_w[e + 1];
            float w2 = csr_w[e + 2],   w3 = csr_w[e + 3];
            float2 v0 = *(const float2*)(xl + (size_t)i0 * D + lane * 2);
            float2 v1 = *(const float2*)(xl + (size_t)i1 * D + lane * 2);
            float2 v2 = *(const float2*)(xl + (size_t)i2 * D + lane * 2);
            float2 v3 = *(const float2*)(xl + (size_t)i3 * D + lane * 2);
            p0 += w0 * v0.x; p1 += w0 * v0.y;
            p2 += w1 * v1.x; p3 += w1 * v1.y;
            p4 += w2 * v2.x; p5 += w2 * v2.y;
            p6 += w3 * v3.x; p7 += w3 * v3.y;
        }
        for (; e < end; e++) {
            int   si = csr_src[e];
            float wv = csr_w[e];
            float2 v = *(const float2*)(xl + (size_t)si * D + lane * 2);
            p0 += wv * v.x; p1 += wv * v.y;
        }
        float a0 = (p0 + p2) + (p4 + p6) + bb0;
        float a1 = (p1 + p3) + (p5 + p7) + bb1;
        if (has_res) {
            float2 rr = *(const float2*)(hr + (size_t)i * D + lane * 2);
            a0 += rr.x; a1 += rr.y;
        }
        *(float2*)(hr + (size_t)i * D + lane * 2) = make_float2(a0, a1);
        s0 += a0; s1 += a1;
        q0 += a0 * a0; q1 += a1 * a1;
    }

    __shared__ float redS[4][D];
    __shared__ float redQ[4][D];
    redS[wave][lane * 2] = s0; redS[wave][lane * 2 + 1] = s1;
    redQ[wave][lane * 2] = q0; redQ[wave][lane * 2 + 1] = q1;
    __syncthreads();
    int t = threadIdx.x;
    if (t < 128) {
        atomicAdd(&stats[t], redS[0][t] + redS[1][t] + redS[2][t] + redS[3][t]);
    } else {
        int c = t - 128;
        atomicAdd(&stats[t], redQ[0][c] + redQ[1][c] + redQ[2][c] + redQ[3][c]);
    }
}

// ---------------------------------------------------------------- finalize stats -> per-col scale/shift
__global__ void finalize_kernel(const float* __restrict__ stats,
                                const float* __restrict__ gamma_l,
                                const float* __restrict__ beta_l,
                                float* __restrict__ AB, float n_inv) {
    int t = threadIdx.x; // 128
    if (t < 128) {
        float mean = stats[t] * n_inv;
        float var  = stats[t + 128] * n_inv - mean * mean;
        var = fmaxf(var, 0.f);
        float rstd = rsqrtf(var + 1e-5f);
        float A = rstd * gamma_l[t];
        float B = beta_l[t] - mean * A;
        AB[t] = A;
        AB[128 + t] = B;
    }
}

// ---------------------------------------------------------------- normalize + relu
__global__ void norm_relu_kernel(const float* __restrict__ hr, const float* __restrict__ AB,
                                 float* __restrict__ hout, int total4) {
    int idx = blockIdx.x * blockDim.x + threadIdx.x;
    int stride = gridDim.x * blockDim.x;
    for (; idx < total4; idx += stride) {
        int c4 = (idx & 31) * 4;
        float4 v = ((const float4*)hr)[idx];
        float4 A = *(const float4*)(AB + c4);
        float4 B = *(const float4*)(AB + 128 + c4);
        v.x = fmaxf(fmaf(v.x, A.x, B.x), 0.f);
        v.y = fmaxf(fmaf(v.y, A.y, B.y), 0.f);
        v.z = fmaxf(fmaf(v.z, A.z, B.z), 0.f);
        v.w = fmaxf(fmaf(v.w, A.w, B.w), 0.f);
        ((float4*)hout)[idx] = v;
    }
}

// ================================================================ launch
extern "C" void kernel_launch(void* const* d_in, const int* in_sizes, int n_in,
                              void* d_out, int out_size, void* d_ws, size_t ws_size,
                              hipStream_t stream) {
    const float* x    = (const float*)d_in[0];
    const int*   eidx = (const int*)d_in[1];     // int32 per harness contract
    const float* ew   = (const float*)d_in[2];
    const float* W    = (const float*)d_in[3];
    const float* b    = (const float*)d_in[4];
    const float* gmm  = (const float*)d_in[5];
    const float* bet  = (const float*)d_in[6];

    const int N = in_sizes[0] / D;
    const int E = in_sizes[2];
    const int L = in_sizes[4] / D;

    // ---- carve workspace
    size_t off = 0;
    auto carve = [&](size_t bytes) -> void* {
        void* p = (char*)d_ws + off;
        off += (bytes + 255) & ~(size_t)255;
        return p;
    };
    float* deg     = (float*)carve((size_t)N * 4);        // becomes dinv
    int*   cnt     = (int*)  carve((size_t)N * 4);
    int*   row_ptr = (int*)  carve((size_t)(N + 1) * 4);
    int*   cursor  = (int*)  carve((size_t)N * 4);
    int*   csr_src = (int*)  carve((size_t)E * 4);
    float* csr_w   = (float*)carve((size_t)E * 4);
    float* xl      = (float*)carve((size_t)N * D * 4);
    float* hr      = (float*)carve((size_t)N * D * 4);
    float* stats   = (float*)carve((size_t)L * 256 * 4);  // per-layer atomic sums
    float* AB      = (float*)carve(256 * 4);
    if (off > ws_size) return; // workspace too small — bail rather than corrupt

    float* hout = (float*)d_out;

    // ---- build normalization + CSR
    hipMemsetAsync(deg, 0, (size_t)N * 4, stream);
    hipMemsetAsync(cnt, 0, (size_t)N * 4, stream);
    hipMemsetAsync(stats, 0, (size_t)L * 256 * 4, stream);
    deg_cnt_kernel<<<2048, 256, 0, stream>>>(eidx + E, ew, deg, cnt, E, N);
    dinv_kernel<<<256, 256, 0, stream>>>(deg, N);
    scan_kernel<<<1, 256, 0, stream>>>(cnt, row_ptr, N);
    hipMemcpyAsync(cursor, row_ptr, (size_t)N * 4, hipMemcpyDeviceToDevice, stream);
    fill_csr_kernel<<<2048, 256, 0, stream>>>(eidx, ew, deg, cursor, csr_src, csr_w, E, N);

    // ---- layers
    const float n_inv = 1.f / (float)N;
    const float* Hin = x;
    for (int l = 0; l < L; l++) {
        gemm128_kernel<<<1024, 256, 0, stream>>>(Hin, W + (size_t)l * D * D, xl, N);
        agg_kernel<<<AGG_BLOCKS, 256, 0, stream>>>(xl, row_ptr, csr_src, csr_w,
                                                   b + (size_t)l * D, hr, stats + (size_t)l * 256,
                                                   N, l > 0 ? 1 : 0);
        finalize_kernel<<<1, 128, 0, stream>>>(stats + (size_t)l * 256,
                                               gmm + (size_t)l * D, bet + (size_t)l * D,
                                               AB, n_inv);
        norm_relu_kernel<<<1024, 256, 0, stream>>>(hr, AB, hout, N * (D / 4));
        Hin = hout;
    }
}

// Round 4
// 881.009 us; speedup vs baseline: 2.4321x; 1.0970x over previous
//
#include <hip/hip_runtime.h>
#include <hip/hip_bf16.h>

#define D 128
#define AGG_BLOCKS 2048

// ---------------------------------------------------------------- count in-degree (int atomics only)
__global__ void cnt_kernel(const int* __restrict__ dst_idx,
                           int* __restrict__ cnt, int E, int N) {
    int e = blockIdx.x * blockDim.x + threadIdx.x;
    int stride = gridDim.x * blockDim.x;
    for (; e < E; e += stride) {
        int d = dst_idx[e];
        if ((unsigned)d < (unsigned)N) atomicAdd(&cnt[d], 1);
    }
}

// ---------------------------------------------------------------- exclusive scan (single block, 1024 thr)
__global__ void scan_kernel(const int* __restrict__ cnt, int* __restrict__ row_ptr, int n) {
    __shared__ int s[1024];
    int t = threadIdx.x;
    int chunk = (n + 1023) / 1024;
    int lo = t * chunk;
    int hi = lo + chunk; if (hi > n) hi = n;
    int sum = 0;
    for (int i = lo; i < hi; i++) sum += cnt[i];
    s[t] = sum;
    __syncthreads();
    for (int off = 1; off < 1024; off <<= 1) {
        int v = (t >= off) ? s[t - off] : 0;
        __syncthreads();
        s[t] += v;
        __syncthreads();
    }
    int run = (t == 0) ? 0 : s[t - 1];
    for (int i = lo; i < hi; i++) { row_ptr[i] = run; run += cnt[i]; }
    if (t == 1023) row_ptr[n] = run;
}

// ---------------------------------------------------------------- fill CSR with RAW weights (counting sort by dst)
__global__ void fill_csr_kernel(const int* __restrict__ idx,
                                const float* __restrict__ w,
                                int* __restrict__ cursor,
                                int* __restrict__ csr_src, float* __restrict__ csr_w,
                                int E, int N) {
    int e = blockIdx.x * blockDim.x + threadIdx.x;
    int stride = gridDim.x * blockDim.x;
    for (; e < E; e += stride) {
        int s = idx[e];
        int d = idx[(size_t)E + e];
        if ((unsigned)s >= (unsigned)N || (unsigned)d >= (unsigned)N) continue;
        int p = atomicAdd(&cursor[d], 1);
        csr_src[p] = s;
        csr_w[p]   = w[e];
    }
}

// ---------------------------------------------------------------- dinv[i] = rsqrt(sum of row i raw weights)
__global__ void dinv_from_csr_kernel(const int* __restrict__ row_ptr,
                                     const float* __restrict__ csr_w,
                                     float* __restrict__ dinv, int n) {
    int gwave = (blockIdx.x * blockDim.x + threadIdx.x) >> 6;
    int lane  = threadIdx.x & 63;
    int nwaves = (gridDim.x * blockDim.x) >> 6;
    for (int i = gwave; i < n; i += nwaves) {
        int beg = row_ptr[i], end = row_ptr[i + 1];
        float s = 0.f;
        for (int e = beg + lane; e < end; e += 64) s += csr_w[e];
        #pragma unroll
        for (int off = 32; off; off >>= 1) s += __shfl_down(s, off);
        if (lane == 0) dinv[i] = (s > 0.f) ? rsqrtf(s) : 0.f;
    }
}

// ---------------------------------------------------------------- csr_w[e] *= dinv[dst]*dinv[src]
__global__ void scale_csr_kernel(const int* __restrict__ row_ptr,
                                 const int* __restrict__ csr_src,
                                 float* __restrict__ csr_w,
                                 const float* __restrict__ dinv, int n) {
    int gwave = (blockIdx.x * blockDim.x + threadIdx.x) >> 6;
    int lane  = threadIdx.x & 63;
    int nwaves = (gridDim.x * blockDim.x) >> 6;
    for (int i = gwave; i < n; i += nwaves) {
        int beg = row_ptr[i], end = row_ptr[i + 1];
        float di = dinv[i];
        for (int e = beg + lane; e < end; e += 64)
            csr_w[e] *= di * dinv[csr_src[e]];
    }
}

// ---------------------------------------------------------------- GEMM: out = act(H) @ Wl
// act = identity (AB==nullptr) or per-column relu(h*A+B) fused on load.
__global__ void gemm128_kernel(const float* __restrict__ H, const float* __restrict__ Wl,
                               const float* __restrict__ AB,
                               float* __restrict__ out, int n) {
    __shared__ float Ws[D * D];      // 64 KiB
    __shared__ float hs[16][D];      // 8 KiB
    int t = threadIdx.x;
    for (int i = t; i < D * D / 4; i += 256)
        ((float4*)Ws)[i] = ((const float4*)Wl)[i];
    __syncthreads();

    int r  = t >> 5;   // 0..7 -> rows r and r+8
    int cg = t & 31;   // column group of 4
    for (int base = blockIdx.x * 16; base < n; base += gridDim.x * 16) {
        int rows = n - base; if (rows > 16) rows = 16;
        for (int i = t; i < 16 * 32; i += 256) {
            int rr = i >> 5, cc = i & 31;
            if (rr < rows) {
                float4 v = *(const float4*)(H + (size_t)(base + rr) * D + cc * 4);
                if (AB) {
                    float4 A = *(const float4*)(AB + cc * 4);
                    float4 B = *(const float4*)(AB + 128 + cc * 4);
                    v.x = fmaxf(fmaf(v.x, A.x, B.x), 0.f);
                    v.y = fmaxf(fmaf(v.y, A.y, B.y), 0.f);
                    v.z = fmaxf(fmaf(v.z, A.z, B.z), 0.f);
                    v.w = fmaxf(fmaf(v.w, A.w, B.w), 0.f);
                }
                ((float4*)hs)[i] = v;
            }
        }
        __syncthreads();
        float4 acc0 = make_float4(0.f, 0.f, 0.f, 0.f);
        float4 acc1 = make_float4(0.f, 0.f, 0.f, 0.f);
        #pragma unroll 8
        for (int k = 0; k < D; k++) {
            float h0 = hs[r][k];
            float h1 = hs[r + 8][k];
            float4 wv = *(const float4*)&Ws[k * D + cg * 4];
            acc0.x += h0 * wv.x; acc0.y += h0 * wv.y;
            acc0.z += h0 * wv.z; acc0.w += h0 * wv.w;
            acc1.x += h1 * wv.x; acc1.y += h1 * wv.y;
            acc1.z += h1 * wv.z; acc1.w += h1 * wv.w;
        }
        if (r < rows)
            *(float4*)(out + (size_t)(base + r) * D + cg * 4) = acc0;
        if (r + 8 < rows)
            *(float4*)(out + (size_t)(base + r + 8) * D + cg * 4) = acc1;
        __syncthreads();
    }
}

// ---------------------------------------------------------------- pull aggregation + bias + residual + col-stats
__global__ void agg_kernel(const float* __restrict__ xl,
                           const int* __restrict__ row_ptr,
                           const int* __restrict__ csr_src,
                           const float* __restrict__ csr_w,
                           const float* __restrict__ bvec,
                           float* __restrict__ hr,        // in(res)/out
                           float* __restrict__ stats,     // [256]: sum | sumsq (atomic)
                           int n, int has_res) {
    int wave = threadIdx.x >> 6;
    int lane = threadIdx.x & 63;
    int gwave = blockIdx.x * 4 + wave;
    int nwaves = gridDim.x * 4;

    float bb0 = bvec[lane * 2], bb1 = bvec[lane * 2 + 1];
    float s0 = 0.f, s1 = 0.f, q0 = 0.f, q1 = 0.f;

    for (int i = gwave; i < n; i += nwaves) {
        int beg = row_ptr[i], end = row_ptr[i + 1];
        float p0 = 0.f, p1 = 0.f, p2 = 0.f, p3 = 0.f;
        float p4 = 0.f, p5 = 0.f, p6 = 0.f, p7 = 0.f;
        int e = beg;
        int e4 = beg + ((end - beg) & ~3);
        for (; e < e4; e += 4) {
            int   i0 = csr_src[e],     i1 = csr_src[e + 1];
            int   i2 = csr_src[e + 2], i3 = csr_src[e + 3];
            float w0 = csr_w[e],       w1 = csr_w[e + 1];
            float w2 = csr_w[e + 2],   w3 = csr_w[e + 3];
            float2 v0 = *(const float2*)(xl + (size_t)i0 * D + lane * 2);
            float2 v1 = *(const float2*)(xl + (size_t)i1 * D + lane * 2);
            float2 v2 = *(const float2*)(xl + (size_t)i2 * D + lane * 2);
            float2 v3 = *(const float2*)(xl + (size_t)i3 * D + lane * 2);
            p0 += w0 * v0.x; p1 += w0 * v0.y;
            p2 += w1 * v1.x; p3 += w1 * v1.y;
            p4 += w2 * v2.x; p5 += w2 * v2.y;
            p6 += w3 * v3.x; p7 += w3 * v3.y;
        }
        for (; e < end; e++) {
            int   si = csr_src[e];
            float wv = csr_w[e];
            float2 v = *(const float2*)(xl + (size_t)si * D + lane * 2);
            p0 += wv * v.x; p1 += wv * v.y;
        }
        float a0 = (p0 + p2) + (p4 + p6) + bb0;
        float a1 = (p1 + p3) + (p5 + p7) + bb1;
        if (has_res) {
            float2 rr = *(const float2*)(hr + (size_t)i * D + lane * 2);
            a0 += rr.x; a1 += rr.y;
        }
        *(float2*)(hr + (size_t)i * D + lane * 2) = make_float2(a0, a1);
        s0 += a0; s1 += a1;
        q0 += a0 * a0; q1 += a1 * a1;
    }

    __shared__ float redS[4][D];
    __shared__ float redQ[4][D];
    redS[wave][lane * 2] = s0; redS[wave][lane * 2 + 1] = s1;
    redQ[wave][lane * 2] = q0; redQ[wave][lane * 2 + 1] = q1;
    __syncthreads();
    int t = threadIdx.x;
    if (t < 128) {
        atomicAdd(&stats[t], redS[0][t] + redS[1][t] + redS[2][t] + redS[3][t]);
    } else {
        int c = t - 128;
        atomicAdd(&stats[t], redQ[0][c] + redQ[1][c] + redQ[2][c] + redQ[3][c]);
    }
}

// ---------------------------------------------------------------- finalize stats -> per-col scale/shift
__global__ void finalize_kernel(const float* __restrict__ stats,
                                const float* __restrict__ gamma_l,
                                const float* __restrict__ beta_l,
                                float* __restrict__ AB, float n_inv) {
    int t = threadIdx.x; // 128
    if (t < 128) {
        float mean = stats[t] * n_inv;
        float var  = stats[t + 128] * n_inv - mean * mean;
        var = fmaxf(var, 0.f);
        float rstd = rsqrtf(var + 1e-5f);
        float A = rstd * gamma_l[t];
        float B = beta_l[t] - mean * A;
        AB[t] = A;
        AB[128 + t] = B;
    }
}

// ---------------------------------------------------------------- normalize + relu (final layer only)
__global__ void norm_relu_kernel(const float* __restrict__ hr, const float* __restrict__ AB,
                                 float* __restrict__ hout, int total4) {
    int idx = blockIdx.x * blockDim.x + threadIdx.x;
    int stride = gridDim.x * blockDim.x;
    for (; idx < total4; idx += stride) {
        int c4 = (idx & 31) * 4;
        float4 v = ((const float4*)hr)[idx];
        float4 A = *(const float4*)(AB + c4);
        float4 B = *(const float4*)(AB + 128 + c4);
        v.x = fmaxf(fmaf(v.x, A.x, B.x), 0.f);
        v.y = fmaxf(fmaf(v.y, A.y, B.y), 0.f);
        v.z = fmaxf(fmaf(v.z, A.z, B.z), 0.f);
        v.w = fmaxf(fmaf(v.w, A.w, B.w), 0.f);
        ((float4*)hout)[idx] = v;
    }
}

// ================================================================ launch
extern "C" void kernel_launch(void* const* d_in, const int* in_sizes, int n_in,
                              void* d_out, int out_size, void* d_ws, size_t ws_size,
                              hipStream_t stream) {
    const float* x    = (const float*)d_in[0];
    const int*   eidx = (const int*)d_in[1];     // int32 per harness contract
    const float* ew   = (const float*)d_in[2];
    const float* W    = (const float*)d_in[3];
    const float* b    = (const float*)d_in[4];
    const float* gmm  = (const float*)d_in[5];
    const float* bet  = (const float*)d_in[6];

    const int N = in_sizes[0] / D;
    const int E = in_sizes[2];
    const int L = in_sizes[4] / D;

    // ---- carve workspace
    size_t off = 0;
    auto carve = [&](size_t bytes) -> void* {
        void* p = (char*)d_ws + off;
        off += (bytes + 255) & ~(size_t)255;
        return p;
    };
    float* dinv    = (float*)carve((size_t)N * 4);
    int*   cnt     = (int*)  carve((size_t)N * 4);
    int*   row_ptr = (int*)  carve((size_t)(N + 1) * 4);
    int*   cursor  = (int*)  carve((size_t)N * 4);
    int*   csr_src = (int*)  carve((size_t)E * 4);
    float* csr_w   = (float*)carve((size_t)E * 4);
    float* xl      = (float*)carve((size_t)N * D * 4);
    float* hr      = (float*)carve((size_t)N * D * 4);
    float* stats   = (float*)carve((size_t)L * 256 * 4);  // per-layer atomic sums
    float* ABbuf   = (float*)carve((size_t)L * 256 * 4);  // per-layer scale/shift
    if (off > ws_size) return;

    float* hout = (float*)d_out;

    // ---- build CSR + normalization
    hipMemsetAsync(cnt, 0, (size_t)N * 4, stream);
    hipMemsetAsync(stats, 0, (size_t)L * 256 * 4, stream);
    cnt_kernel<<<1024, 256, 0, stream>>>(eidx + E, cnt, E, N);
    scan_kernel<<<1, 1024, 0, stream>>>(cnt, row_ptr, N);
    hipMemcpyAsync(cursor, row_ptr, (size_t)N * 4, hipMemcpyDeviceToDevice, stream);
    fill_csr_kernel<<<2048, 256, 0, stream>>>(eidx, ew, cursor, csr_src, csr_w, E, N);
    dinv_from_csr_kernel<<<1024, 256, 0, stream>>>(row_ptr, csr_w, dinv, N);
    scale_csr_kernel<<<1024, 256, 0, stream>>>(row_ptr, csr_src, csr_w, dinv, N);

    // ---- layers
    const float n_inv = 1.f / (float)N;
    for (int l = 0; l < L; l++) {
        const float* Hin = (l == 0) ? x : hr;
        const float* ABl = (l == 0) ? nullptr : ABbuf + (size_t)(l - 1) * 256;
        gemm128_kernel<<<1024, 256, 0, stream>>>(Hin, W + (size_t)l * D * D, ABl, xl, N);
        agg_kernel<<<AGG_BLOCKS, 256, 0, stream>>>(xl, row_ptr, csr_src, csr_w,
                                                   b + (size_t)l * D, hr, stats + (size_t)l * 256,
                                                   N, l > 0 ? 1 : 0);
        finalize_kernel<<<1, 128, 0, stream>>>(stats + (size_t)l * 256,
                                               gmm + (size_t)l * D, bet + (size_t)l * D,
                                               ABbuf + (size_t)l * 256, n_inv);
    }
    norm_relu_kernel<<<1024, 256, 0, stream>>>(hr, ABbuf + (size_t)(L - 1) * 256,
                                               hout, N * (D / 4));
}

// Round 5
// 832.430 us; speedup vs baseline: 2.5740x; 1.0584x over previous
//
#include <hip/hip_runtime.h>
#include <hip/hip_bf16.h>

#define D 128
#define AGG_BLOCKS 2048

// pack two f32 -> bf16 pair (RNE)
__device__ inline unsigned bf16pair(float x, float y) {
    unsigned xb = __float_as_uint(x), yb = __float_as_uint(y);
    xb = (xb + 0x7FFFu + ((xb >> 16) & 1u)) >> 16;
    yb = (yb + 0x7FFFu + ((yb >> 16) & 1u)) >> 16;
    return xb | (yb << 16);
}

// ---------------------------------------------------------------- count in-degree (int atomics only)
__global__ void cnt_kernel(const int* __restrict__ dst_idx,
                           int* __restrict__ cnt, int E, int N) {
    int e = blockIdx.x * blockDim.x + threadIdx.x;
    int stride = gridDim.x * blockDim.x;
    for (; e < E; e += stride) {
        int d = dst_idx[e];
        if ((unsigned)d < (unsigned)N) atomicAdd(&cnt[d], 1);
    }
}

// ---------------------------------------------------------------- exclusive scan (single block, 1024 thr)
__global__ void scan_kernel(const int* __restrict__ cnt, int* __restrict__ row_ptr, int n) {
    __shared__ int s[1024];
    int t = threadIdx.x;
    int chunk = (n + 1023) / 1024;
    int lo = t * chunk;
    int hi = lo + chunk; if (hi > n) hi = n;
    int sum = 0;
    for (int i = lo; i < hi; i++) sum += cnt[i];
    s[t] = sum;
    __syncthreads();
    for (int off = 1; off < 1024; off <<= 1) {
        int v = (t >= off) ? s[t - off] : 0;
        __syncthreads();
        s[t] += v;
        __syncthreads();
    }
    int run = (t == 0) ? 0 : s[t - 1];
    for (int i = lo; i < hi; i++) { row_ptr[i] = run; run += cnt[i]; }
    if (t == 1023) row_ptr[n] = run;
}

// ---------------------------------------------------------------- fill CSR: packed (src, raw w) int2
__global__ void fill_csr_kernel(const int* __restrict__ idx,
                                const float* __restrict__ w,
                                int* __restrict__ cursor,
                                int2* __restrict__ csr_ew,
                                int E, int N) {
    int e = blockIdx.x * blockDim.x + threadIdx.x;
    int stride = gridDim.x * blockDim.x;
    for (; e < E; e += stride) {
        int s = idx[e];
        int d = idx[(size_t)E + e];
        if ((unsigned)s >= (unsigned)N || (unsigned)d >= (unsigned)N) continue;
        int p = atomicAdd(&cursor[d], 1);
        csr_ew[p] = make_int2(s, __float_as_int(w[e]));
    }
}

// ---------------------------------------------------------------- dinv[i] = rsqrt(sum of row i raw weights)
__global__ void dinv_from_csr_kernel(const int* __restrict__ row_ptr,
                                     const int2* __restrict__ csr_ew,
                                     float* __restrict__ dinv, int n) {
    int gwave = (blockIdx.x * blockDim.x + threadIdx.x) >> 6;
    int lane  = threadIdx.x & 63;
    int nwaves = (gridDim.x * blockDim.x) >> 6;
    for (int i = gwave; i < n; i += nwaves) {
        int beg = row_ptr[i], end = row_ptr[i + 1];
        float s = 0.f;
        for (int e = beg + lane; e < end; e += 64) s += __int_as_float(csr_ew[e].y);
        #pragma unroll
        for (int off = 32; off; off >>= 1) s += __shfl_down(s, off);
        if (lane == 0) dinv[i] = (s > 0.f) ? rsqrtf(s) : 0.f;
    }
}

// ---------------------------------------------------------------- csr_w *= dinv[dst]*dinv[src]
__global__ void scale_csr_kernel(const int* __restrict__ row_ptr,
                                 int2* __restrict__ csr_ew,
                                 const float* __restrict__ dinv, int n) {
    int gwave = (blockIdx.x * blockDim.x + threadIdx.x) >> 6;
    int lane  = threadIdx.x & 63;
    int nwaves = (gridDim.x * blockDim.x) >> 6;
    for (int i = gwave; i < n; i += nwaves) {
        int beg = row_ptr[i], end = row_ptr[i + 1];
        float di = dinv[i];
        for (int e = beg + lane; e < end; e += 64) {
            int2 c = csr_ew[e];
            csr_ew[e].y = __float_as_int(__int_as_float(c.y) * di * dinv[c.x]);
        }
    }
}

// ---------------------------------------------------------------- GEMM: outb = bf16pack( act(H) @ Wl )
// act = identity (AB==nullptr) or per-column relu(h*A+B) fused on load.
__global__ void gemm128_kernel(const float* __restrict__ H, const float* __restrict__ Wl,
                               const float* __restrict__ AB,
                               unsigned* __restrict__ outb, int n) {
    __shared__ float Ws[D * D];      // 64 KiB
    __shared__ float hs[16][D];      // 8 KiB
    int t = threadIdx.x;
    for (int i = t; i < D * D / 4; i += 256)
        ((float4*)Ws)[i] = ((const float4*)Wl)[i];
    __syncthreads();

    int r  = t >> 5;   // 0..7 -> rows r and r+8
    int cg = t & 31;   // column group of 4
    for (int base = blockIdx.x * 16; base < n; base += gridDim.x * 16) {
        int rows = n - base; if (rows > 16) rows = 16;
        for (int i = t; i < 16 * 32; i += 256) {
            int rr = i >> 5, cc = i & 31;
            if (rr < rows) {
                float4 v = *(const float4*)(H + (size_t)(base + rr) * D + cc * 4);
                if (AB) {
                    float4 A = *(const float4*)(AB + cc * 4);
                    float4 B = *(const float4*)(AB + 128 + cc * 4);
                    v.x = fmaxf(fmaf(v.x, A.x, B.x), 0.f);
                    v.y = fmaxf(fmaf(v.y, A.y, B.y), 0.f);
                    v.z = fmaxf(fmaf(v.z, A.z, B.z), 0.f);
                    v.w = fmaxf(fmaf(v.w, A.w, B.w), 0.f);
                }
                ((float4*)hs)[i] = v;
            }
        }
        __syncthreads();
        float4 acc0 = make_float4(0.f, 0.f, 0.f, 0.f);
        float4 acc1 = make_float4(0.f, 0.f, 0.f, 0.f);
        #pragma unroll 8
        for (int k = 0; k < D; k++) {
            float h0 = hs[r][k];
            float h1 = hs[r + 8][k];
            float4 wv = *(const float4*)&Ws[k * D + cg * 4];
            acc0.x += h0 * wv.x; acc0.y += h0 * wv.y;
            acc0.z += h0 * wv.z; acc0.w += h0 * wv.w;
            acc1.x += h1 * wv.x; acc1.y += h1 * wv.y;
            acc1.z += h1 * wv.z; acc1.w += h1 * wv.w;
        }
        if (r < rows) {
            uint2 u = make_uint2(bf16pair(acc0.x, acc0.y), bf16pair(acc0.z, acc0.w));
            *(uint2*)(outb + (size_t)(base + r) * 64 + cg * 2) = u;
        }
        if (r + 8 < rows) {
            uint2 u = make_uint2(bf16pair(acc1.x, acc1.y), bf16pair(acc1.z, acc1.w));
            *(uint2*)(outb + (size_t)(base + r + 8) * 64 + cg * 2) = u;
        }
        __syncthreads();
    }
}

// ---------------------------------------------------------------- pull aggregation + bias + residual + col-stats
// one wave per dst node; lane owns cols (2l,2l+1) as one packed uint; 8-deep gather pipeline
__global__ void agg_kernel(const unsigned* __restrict__ xlb,
                           const int* __restrict__ row_ptr,
                           const int2* __restrict__ csr_ew,
                           const float* __restrict__ bvec,
                           float* __restrict__ hr,        // in(res)/out, f32
                           float* __restrict__ stats,     // [256]: sum | sumsq (atomic)
                           int n, int has_res) {
    int wave = threadIdx.x >> 6;
    int lane = threadIdx.x & 63;
    int gwave = blockIdx.x * 4 + wave;
    int nwaves = gridDim.x * 4;

    float bb0 = bvec[lane * 2], bb1 = bvec[lane * 2 + 1];
    float s0 = 0.f, s1 = 0.f, q0 = 0.f, q1 = 0.f;

    for (int i = gwave; i < n; i += nwaves) {
        int beg = row_ptr[i], end = row_ptr[i + 1];
        float pa0 = 0.f, pa1 = 0.f, pb0 = 0.f, pb1 = 0.f;
        float pc0 = 0.f, pc1 = 0.f, pd0 = 0.f, pd1 = 0.f;
        int e = beg;
        int e8 = beg + ((end - beg) & ~7);
        for (; e < e8; e += 8) {
            int2 c0 = csr_ew[e + 0], c1 = csr_ew[e + 1];
            int2 c2 = csr_ew[e + 2], c3 = csr_ew[e + 3];
            int2 c4 = csr_ew[e + 4], c5 = csr_ew[e + 5];
            int2 c6 = csr_ew[e + 6], c7 = csr_ew[e + 7];
            unsigned g0 = xlb[(size_t)c0.x * 64 + lane];
            unsigned g1 = xlb[(size_t)c1.x * 64 + lane];
            unsigned g2 = xlb[(size_t)c2.x * 64 + lane];
            unsigned g3 = xlb[(size_t)c3.x * 64 + lane];
            unsigned g4 = xlb[(size_t)c4.x * 64 + lane];
            unsigned g5 = xlb[(size_t)c5.x * 64 + lane];
            unsigned g6 = xlb[(size_t)c6.x * 64 + lane];
            unsigned g7 = xlb[(size_t)c7.x * 64 + lane];
            float w0 = __int_as_float(c0.y), w1 = __int_as_float(c1.y);
            float w2 = __int_as_float(c2.y), w3 = __int_as_float(c3.y);
            float w4 = __int_as_float(c4.y), w5 = __int_as_float(c5.y);
            float w6 = __int_as_float(c6.y), w7 = __int_as_float(c7.y);
            pa0 += w0 * __uint_as_float(g0 << 16); pa1 += w0 * __uint_as_float(g0 & 0xFFFF0000u);
            pb0 += w1 * __uint_as_float(g1 << 16); pb1 += w1 * __uint_as_float(g1 & 0xFFFF0000u);
            pc0 += w2 * __uint_as_float(g2 << 16); pc1 += w2 * __uint_as_float(g2 & 0xFFFF0000u);
            pd0 += w3 * __uint_as_float(g3 << 16); pd1 += w3 * __uint_as_float(g3 & 0xFFFF0000u);
            pa0 += w4 * __uint_as_float(g4 << 16); pa1 += w4 * __uint_as_float(g4 & 0xFFFF0000u);
            pb0 += w5 * __uint_as_float(g5 << 16); pb1 += w5 * __uint_as_float(g5 & 0xFFFF0000u);
            pc0 += w6 * __uint_as_float(g6 << 16); pc1 += w6 * __uint_as_float(g6 & 0xFFFF0000u);
            pd0 += w7 * __uint_as_float(g7 << 16); pd1 += w7 * __uint_as_float(g7 & 0xFFFF0000u);
        }
        for (; e < end; e++) {
            int2 c = csr_ew[e];
            float wv = __int_as_float(c.y);
            unsigned g = xlb[(size_t)c.x * 64 + lane];
            pa0 += wv * __uint_as_float(g << 16);
            pa1 += wv * __uint_as_float(g & 0xFFFF0000u);
        }
        float a0 = (pa0 + pb0) + (pc0 + pd0) + bb0;
        float a1 = (pa1 + pb1) + (pc1 + pd1) + bb1;
        if (has_res) {
            float2 rr = *(const float2*)(hr + (size_t)i * D + lane * 2);
            a0 += rr.x; a1 += rr.y;
        }
        *(float2*)(hr + (size_t)i * D + lane * 2) = make_float2(a0, a1);
        s0 += a0; s1 += a1;
        q0 += a0 * a0; q1 += a1 * a1;
    }

    __shared__ float redS[4][D];
    __shared__ float redQ[4][D];
    redS[wave][lane * 2] = s0; redS[wave][lane * 2 + 1] = s1;
    redQ[wave][lane * 2] = q0; redQ[wave][lane * 2 + 1] = q1;
    __syncthreads();
    int t = threadIdx.x;
    if (t < 128) {
        atomicAdd(&stats[t], redS[0][t] + redS[1][t] + redS[2][t] + redS[3][t]);
    } else {
        int c = t - 128;
        atomicAdd(&stats[t], redQ[0][c] + redQ[1][c] + redQ[2][c] + redQ[3][c]);
    }
}

// ---------------------------------------------------------------- finalize stats -> per-col scale/shift
__global__ void finalize_kernel(const float* __restrict__ stats,
                                const float* __restrict__ gamma_l,
                                const float* __restrict__ beta_l,
                                float* __restrict__ AB, float n_inv) {
    int t = threadIdx.x; // 128
    if (t < 128) {
        float mean = stats[t] * n_inv;
        float var  = stats[t + 128] * n_inv - mean * mean;
        var = fmaxf(var, 0.f);
        float rstd = rsqrtf(var + 1e-5f);
        float A = rstd * gamma_l[t];
        float B = beta_l[t] - mean * A;
        AB[t] = A;
        AB[128 + t] = B;
    }
}

// ---------------------------------------------------------------- normalize + relu (final layer only)
__global__ void norm_relu_kernel(const float* __restrict__ hr, const float* __restrict__ AB,
                                 float* __restrict__ hout, int total4) {
    int idx = blockIdx.x * blockDim.x + threadIdx.x;
    int stride = gridDim.x * blockDim.x;
    for (; idx < total4; idx += stride) {
        int c4 = (idx & 31) * 4;
        float4 v = ((const float4*)hr)[idx];
        float4 A = *(const float4*)(AB + c4);
        float4 B = *(const float4*)(AB + 128 + c4);
        v.x = fmaxf(fmaf(v.x, A.x, B.x), 0.f);
        v.y = fmaxf(fmaf(v.y, A.y, B.y), 0.f);
        v.z = fmaxf(fmaf(v.z, A.z, B.z), 0.f);
        v.w = fmaxf(fmaf(v.w, A.w, B.w), 0.f);
        ((float4*)hout)[idx] = v;
    }
}

// ================================================================ launch
extern "C" void kernel_launch(void* const* d_in, const int* in_sizes, int n_in,
                              void* d_out, int out_size, void* d_ws, size_t ws_size,
                              hipStream_t stream) {
    const float* x    = (const float*)d_in[0];
    const int*   eidx = (const int*)d_in[1];
    const float* ew   = (const float*)d_in[2];
    const float* W    = (const float*)d_in[3];
    const float* b    = (const float*)d_in[4];
    const float* gmm  = (const float*)d_in[5];
    const float* bet  = (const float*)d_in[6];

    const int N = in_sizes[0] / D;
    const int E = in_sizes[2];
    const int L = in_sizes[4] / D;

    // ---- carve workspace
    size_t off = 0;
    auto carve = [&](size_t bytes) -> void* {
        void* p = (char*)d_ws + off;
        off += (bytes + 255) & ~(size_t)255;
        return p;
    };
    float*    dinv    = (float*)carve((size_t)N * 4);
    int*      cnt     = (int*)  carve((size_t)N * 4);
    int*      row_ptr = (int*)  carve((size_t)(N + 1) * 4);
    int*      cursor  = (int*)  carve((size_t)N * 4);
    int2*     csr_ew  = (int2*) carve((size_t)E * 8);
    unsigned* xlb     = (unsigned*)carve((size_t)N * 64 * 4);   // bf16-packed xl
    float*    hr      = (float*)carve((size_t)N * D * 4);
    float*    stats   = (float*)carve((size_t)L * 256 * 4);
    float*    ABbuf   = (float*)carve((size_t)L * 256 * 4);
    if (off > ws_size) return;

    float* hout = (float*)d_out;

    // ---- build CSR + normalization
    hipMemsetAsync(cnt, 0, (size_t)N * 4, stream);
    hipMemsetAsync(stats, 0, (size_t)L * 256 * 4, stream);
    cnt_kernel<<<1024, 256, 0, stream>>>(eidx + E, cnt, E, N);
    scan_kernel<<<1, 1024, 0, stream>>>(cnt, row_ptr, N);
    hipMemcpyAsync(cursor, row_ptr, (size_t)N * 4, hipMemcpyDeviceToDevice, stream);
    fill_csr_kernel<<<2048, 256, 0, stream>>>(eidx, ew, cursor, csr_ew, E, N);
    dinv_from_csr_kernel<<<1024, 256, 0, stream>>>(row_ptr, csr_ew, dinv, N);
    scale_csr_kernel<<<1024, 256, 0, stream>>>(row_ptr, csr_ew, dinv, N);

    // ---- layers
    const float n_inv = 1.f / (float)N;
    for (int l = 0; l < L; l++) {
        const float* Hin = (l == 0) ? x : hr;
        const float* ABl = (l == 0) ? nullptr : ABbuf + (size_t)(l - 1) * 256;
        gemm128_kernel<<<1024, 256, 0, stream>>>(Hin, W + (size_t)l * D * D, ABl, xlb, N);
        agg_kernel<<<AGG_BLOCKS, 256, 0, stream>>>(xlb, row_ptr, csr_ew,
                                                   b + (size_t)l * D, hr, stats + (size_t)l * 256,
                                                   N, l > 0 ? 1 : 0);
        finalize_kernel<<<1, 128, 0, stream>>>(stats + (size_t)l * 256,
                                               gmm + (size_t)l * D, bet + (size_t)l * D,
                                               ABbuf + (size_t)l * 256, n_inv);
    }
    norm_relu_kernel<<<1024, 256, 0, stream>>>(hr, ABbuf + (size_t)(L - 1) * 256,
                                               hout, N * (D / 4));
}

// Round 6
// 574.006 us; speedup vs baseline: 3.7329x; 1.4502x over previous
//
#include <hip/hip_runtime.h>
#include <hip/hip_bf16.h>

#define D 128
#define AGG_BLOCKS 2048

// pack two f32 -> bf16 pair (RNE)
__device__ inline unsigned bf16pair(float x, float y) {
    unsigned xb = __float_as_uint(x), yb = __float_as_uint(y);
    xb = (xb + 0x7FFFu + ((xb >> 16) & 1u)) >> 16;
    yb = (yb + 0x7FFFu + ((yb >> 16) & 1u)) >> 16;
    return xb | (yb << 16);
}

// ---------------------------------------------------------------- pass 0: 256-bin histogram of dst>>8
__global__ void hist_kernel(const int* __restrict__ dst_idx,
                            int* __restrict__ bucket_cnt, int E, int N) {
    __shared__ int h[256];
    int t = threadIdx.x;
    h[t] = 0;
    __syncthreads();
    int e = blockIdx.x * blockDim.x + t;
    int stride = gridDim.x * blockDim.x;
    for (; e < E; e += stride) {
        int d = dst_idx[e];
        if ((unsigned)d < (unsigned)N) atomicAdd(&h[d >> 8], 1);
    }
    __syncthreads();
    if (h[t]) atomicAdd(&bucket_cnt[t], h[t]);
}

// ---------------------------------------------------------------- scan 256 buckets -> base, cursor; row_ptr[N]=total
__global__ void bucket_scan_kernel(const int* __restrict__ bucket_cnt,
                                   int* __restrict__ bucket_base,
                                   int* __restrict__ bucket_cursor,
                                   int* __restrict__ row_ptr, int N) {
    __shared__ int s[256];
    int t = threadIdx.x;
    s[t] = bucket_cnt[t];
    __syncthreads();
    for (int off = 1; off < 256; off <<= 1) {
        int v = (t >= off) ? s[t - off] : 0;
        __syncthreads();
        s[t] += v;
        __syncthreads();
    }
    int ex = t ? s[t - 1] : 0;
    bucket_base[t]   = ex;
    bucket_cursor[t] = ex;
    if (t == 255) { bucket_base[256] = s[255]; row_ptr[N] = s[255]; }
}

// ---------------------------------------------------------------- pass 1: chunked scatter into coarse buckets
// rec = { src | dstlow<<16 , raw w }, contiguous per (block,bucket)
#define CH 1024
__global__ void pass1_kernel(const int* __restrict__ idx,
                             const float* __restrict__ w,
                             int* __restrict__ bucket_cursor,
                             int2* __restrict__ rec, int E, int N) {
    __shared__ int h[256], bb[256], cur[256];
    const int* dst = idx + E;
    int t = threadIdx.x;
    int nchunks = (E + CH - 1) / CH;
    for (int c = blockIdx.x; c < nchunks; c += gridDim.x) {
        int lo = c * CH;
        int hi = lo + CH; if (hi > E) hi = E;
        h[t] = 0; cur[t] = 0;
        __syncthreads();
        for (int e = lo + t; e < hi; e += 256) {
            int d = dst[e];
            if ((unsigned)d < (unsigned)N) atomicAdd(&h[d >> 8], 1);
        }
        __syncthreads();
        if (h[t]) bb[t] = atomicAdd(&bucket_cursor[t], h[t]);
        __syncthreads();
        for (int e = lo + t; e < hi; e += 256) {
            int d = dst[e];
            if ((unsigned)d >= (unsigned)N) continue;
            int s = idx[e];
            int b = d >> 8;
            int r = atomicAdd(&cur[b], 1);
            rec[bb[b] + r] = make_int2((s & 0xFFFF) | ((d & 255) << 16),
                                       __float_as_int(w[e]));
        }
        __syncthreads();
    }
}

// ---------------------------------------------------------------- pass 2: per-bucket LDS counting sort -> CSR + row_ptr + dinv
__global__ void pass2_kernel(const int2* __restrict__ rec,
                             const int* __restrict__ bucket_base,
                             int2* __restrict__ csr,
                             int* __restrict__ row_ptr,
                             float* __restrict__ dinv, int N) {
    __shared__ int   hist[256], pref[256], cur[256];
    __shared__ float degs[256];
    int b = blockIdx.x;
    int t = threadIdx.x;
    int lo = bucket_base[b], hi = bucket_base[b + 1];
    if (t < 256) { hist[t] = 0; cur[t] = 0; degs[t] = 0.f; }
    __syncthreads();
    for (int e = lo + t; e < hi; e += blockDim.x)
        atomicAdd(&hist[(rec[e].x >> 16) & 255], 1);
    __syncthreads();
    for (int off = 1; off < 256; off <<= 1) {
        int v = 0;
        if (t < 256 && t >= off) v = hist[t - off];
        __syncthreads();
        if (t < 256) hist[t] += v;
        __syncthreads();
    }
    if (t < 256) {
        pref[t] = t ? hist[t - 1] : 0;
        int node = b * 256 + t;
        if (node < N) row_ptr[node] = lo + pref[t];
    }
    __syncthreads();
    for (int e = lo + t; e < hi; e += blockDim.x) {
        int2 rc = rec[e];
        int dl = (rc.x >> 16) & 255;
        int r = atomicAdd(&cur[dl], 1);
        csr[lo + pref[dl] + r] = rc;
        atomicAdd(&degs[dl], __int_as_float(rc.y));
    }
    __syncthreads();
    if (t < 256) {
        int node = b * 256 + t;
        if (node < N) {
            float dg = degs[t];
            dinv[node] = (dg > 0.f) ? rsqrtf(dg) : 0.f;
        }
    }
}

// ---------------------------------------------------------------- csr_w *= dinv[dst]*dinv[src]
__global__ void scale_csr_kernel(const int* __restrict__ row_ptr,
                                 int2* __restrict__ csr_ew,
                                 const float* __restrict__ dinv, int n) {
    int gwave = (blockIdx.x * blockDim.x + threadIdx.x) >> 6;
    int lane  = threadIdx.x & 63;
    int nwaves = (gridDim.x * blockDim.x) >> 6;
    for (int i = gwave; i < n; i += nwaves) {
        int beg = row_ptr[i], end = row_ptr[i + 1];
        float di = dinv[i];
        for (int e = beg + lane; e < end; e += 64) {
            int2 c = csr_ew[e];
            csr_ew[e].y = __float_as_int(__int_as_float(c.y) * di * dinv[c.x & 0xFFFF]);
        }
    }
}

// ---------------------------------------------------------------- GEMM: outb = bf16pack( act(H) @ Wl )
__global__ void gemm128_kernel(const float* __restrict__ H, const float* __restrict__ Wl,
                               const float* __restrict__ AB,
                               unsigned* __restrict__ outb, int n) {
    __shared__ float Ws[D * D];      // 64 KiB
    __shared__ float hs[16][D];      // 8 KiB
    int t = threadIdx.x;
    for (int i = t; i < D * D / 4; i += 256)
        ((float4*)Ws)[i] = ((const float4*)Wl)[i];
    __syncthreads();

    int r  = t >> 5;   // 0..7 -> rows r and r+8
    int cg = t & 31;   // column group of 4
    for (int base = blockIdx.x * 16; base < n; base += gridDim.x * 16) {
        int rows = n - base; if (rows > 16) rows = 16;
        for (int i = t; i < 16 * 32; i += 256) {
            int rr = i >> 5, cc = i & 31;
            if (rr < rows) {
                float4 v = *(const float4*)(H + (size_t)(base + rr) * D + cc * 4);
                if (AB) {
                    float4 A = *(const float4*)(AB + cc * 4);
                    float4 B = *(const float4*)(AB + 128 + cc * 4);
                    v.x = fmaxf(fmaf(v.x, A.x, B.x), 0.f);
                    v.y = fmaxf(fmaf(v.y, A.y, B.y), 0.f);
                    v.z = fmaxf(fmaf(v.z, A.z, B.z), 0.f);
                    v.w = fmaxf(fmaf(v.w, A.w, B.w), 0.f);
                }
                ((float4*)hs)[i] = v;
            }
        }
        __syncthreads();
        float4 acc0 = make_float4(0.f, 0.f, 0.f, 0.f);
        float4 acc1 = make_float4(0.f, 0.f, 0.f, 0.f);
        #pragma unroll 8
        for (int k = 0; k < D; k++) {
            float h0 = hs[r][k];
            float h1 = hs[r + 8][k];
            float4 wv = *(const float4*)&Ws[k * D + cg * 4];
            acc0.x += h0 * wv.x; acc0.y += h0 * wv.y;
            acc0.z += h0 * wv.z; acc0.w += h0 * wv.w;
            acc1.x += h1 * wv.x; acc1.y += h1 * wv.y;
            acc1.z += h1 * wv.z; acc1.w += h1 * wv.w;
        }
        if (r < rows) {
            uint2 u = make_uint2(bf16pair(acc0.x, acc0.y), bf16pair(acc0.z, acc0.w));
            *(uint2*)(outb + (size_t)(base + r) * 64 + cg * 2) = u;
        }
        if (r + 8 < rows) {
            uint2 u = make_uint2(bf16pair(acc1.x, acc1.y), bf16pair(acc1.z, acc1.w));
            *(uint2*)(outb + (size_t)(base + r + 8) * 64 + cg * 2) = u;
        }
        __syncthreads();
    }
}

// ---------------------------------------------------------------- pull aggregation + bias + residual + col-stats
__global__ void agg_kernel(const unsigned* __restrict__ xlb,
                           const int* __restrict__ row_ptr,
                           const int2* __restrict__ csr_ew,
                           const float* __restrict__ bvec,
                           float* __restrict__ hr,        // in(res)/out, f32
                           float* __restrict__ stats,     // [256]: sum | sumsq (atomic)
                           int n, int has_res) {
    int wave = threadIdx.x >> 6;
    int lane = threadIdx.x & 63;
    int gwave = blockIdx.x * 4 + wave;
    int nwaves = gridDim.x * 4;

    float bb0 = bvec[lane * 2], bb1 = bvec[lane * 2 + 1];
    float s0 = 0.f, s1 = 0.f, q0 = 0.f, q1 = 0.f;

    for (int i = gwave; i < n; i += nwaves) {
        int beg = row_ptr[i], end = row_ptr[i + 1];
        float pa0 = 0.f, pa1 = 0.f, pb0 = 0.f, pb1 = 0.f;
        float pc0 = 0.f, pc1 = 0.f, pd0 = 0.f, pd1 = 0.f;
        int e = beg;
        int e8 = beg + ((end - beg) & ~7);
        for (; e < e8; e += 8) {
            int2 c0 = csr_ew[e + 0], c1 = csr_ew[e + 1];
            int2 c2 = csr_ew[e + 2], c3 = csr_ew[e + 3];
            int2 c4 = csr_ew[e + 4], c5 = csr_ew[e + 5];
            int2 c6 = csr_ew[e + 6], c7 = csr_ew[e + 7];
            unsigned g0 = xlb[(size_t)(c0.x & 0xFFFF) * 64 + lane];
            unsigned g1 = xlb[(size_t)(c1.x & 0xFFFF) * 64 + lane];
            unsigned g2 = xlb[(size_t)(c2.x & 0xFFFF) * 64 + lane];
            unsigned g3 = xlb[(size_t)(c3.x & 0xFFFF) * 64 + lane];
            unsigned g4 = xlb[(size_t)(c4.x & 0xFFFF) * 64 + lane];
            unsigned g5 = xlb[(size_t)(c5.x & 0xFFFF) * 64 + lane];
            unsigned g6 = xlb[(size_t)(c6.x & 0xFFFF) * 64 + lane];
            unsigned g7 = xlb[(size_t)(c7.x & 0xFFFF) * 64 + lane];
            float w0 = __int_as_float(c0.y), w1 = __int_as_float(c1.y);
            float w2 = __int_as_float(c2.y), w3 = __int_as_float(c3.y);
            float w4 = __int_as_float(c4.y), w5 = __int_as_float(c5.y);
            float w6 = __int_as_float(c6.y), w7 = __int_as_float(c7.y);
            pa0 += w0 * __uint_as_float(g0 << 16); pa1 += w0 * __uint_as_float(g0 & 0xFFFF0000u);
            pb0 += w1 * __uint_as_float(g1 << 16); pb1 += w1 * __uint_as_float(g1 & 0xFFFF0000u);
            pc0 += w2 * __uint_as_float(g2 << 16); pc1 += w2 * __uint_as_float(g2 & 0xFFFF0000u);
            pd0 += w3 * __uint_as_float(g3 << 16); pd1 += w3 * __uint_as_float(g3 & 0xFFFF0000u);
            pa0 += w4 * __uint_as_float(g4 << 16); pa1 += w4 * __uint_as_float(g4 & 0xFFFF0000u);
            pb0 += w5 * __uint_as_float(g5 << 16); pb1 += w5 * __uint_as_float(g5 & 0xFFFF0000u);
            pc0 += w6 * __uint_as_float(g6 << 16); pc1 += w6 * __uint_as_float(g6 & 0xFFFF0000u);
            pd0 += w7 * __uint_as_float(g7 << 16); pd1 += w7 * __uint_as_float(g7 & 0xFFFF0000u);
        }
        for (; e < end; e++) {
            int2 c = csr_ew[e];
            float wv = __int_as_float(c.y);
            unsigned g = xlb[(size_t)(c.x & 0xFFFF) * 64 + lane];
            pa0 += wv * __uint_as_float(g << 16);
            pa1 += wv * __uint_as_float(g & 0xFFFF0000u);
        }
        float a0 = (pa0 + pb0) + (pc0 + pd0) + bb0;
        float a1 = (pa1 + pb1) + (pc1 + pd1) + bb1;
        if (has_res) {
            float2 rr = *(const float2*)(hr + (size_t)i * D + lane * 2);
            a0 += rr.x; a1 += rr.y;
        }
        *(float2*)(hr + (size_t)i * D + lane * 2) = make_float2(a0, a1);
        s0 += a0; s1 += a1;
        q0 += a0 * a0; q1 += a1 * a1;
    }

    __shared__ float redS[4][D];
    __shared__ float redQ[4][D];
    redS[wave][lane * 2] = s0; redS[wave][lane * 2 + 1] = s1;
    redQ[wave][lane * 2] = q0; redQ[wave][lane * 2 + 1] = q1;
    __syncthreads();
    int t = threadIdx.x;
    if (t < 128) {
        atomicAdd(&stats[t], redS[0][t] + redS[1][t] + redS[2][t] + redS[3][t]);
    } else {
        int c = t - 128;
        atomicAdd(&stats[t], redQ[0][c] + redQ[1][c] + redQ[2][c] + redQ[3][c]);
    }
}

// ---------------------------------------------------------------- finalize stats -> per-col scale/shift
__global__ void finalize_kernel(const float* __restrict__ stats,
                                const float* __restrict__ gamma_l,
                                const float* __restrict__ beta_l,
                                float* __restrict__ AB, float n_inv) {
    int t = threadIdx.x; // 128
    if (t < 128) {
        float mean = stats[t] * n_inv;
        float var  = stats[t + 128] * n_inv - mean * mean;
        var = fmaxf(var, 0.f);
        float rstd = rsqrtf(var + 1e-5f);
        float A = rstd * gamma_l[t];
        float B = beta_l[t] - mean * A;
        AB[t] = A;
        AB[128 + t] = B;
    }
}

// ---------------------------------------------------------------- normalize + relu (final layer only)
__global__ void norm_relu_kernel(const float* __restrict__ hr, const float* __restrict__ AB,
                                 float* __restrict__ hout, int total4) {
    int idx = blockIdx.x * blockDim.x + threadIdx.x;
    int stride = gridDim.x * blockDim.x;
    for (; idx < total4; idx += stride) {
        int c4 = (idx & 31) * 4;
        float4 v = ((const float4*)hr)[idx];
        float4 A = *(const float4*)(AB + c4);
        float4 B = *(const float4*)(AB + 128 + c4);
        v.x = fmaxf(fmaf(v.x, A.x, B.x), 0.f);
        v.y = fmaxf(fmaf(v.y, A.y, B.y), 0.f);
        v.z = fmaxf(fmaf(v.z, A.z, B.z), 0.f);
        v.w = fmaxf(fmaf(v.w, A.w, B.w), 0.f);
        ((float4*)hout)[idx] = v;
    }
}

// ================================================================ launch
extern "C" void kernel_launch(void* const* d_in, const int* in_sizes, int n_in,
                              void* d_out, int out_size, void* d_ws, size_t ws_size,
                              hipStream_t stream) {
    const float* x    = (const float*)d_in[0];
    const int*   eidx = (const int*)d_in[1];
    const float* ew   = (const float*)d_in[2];
    const float* W    = (const float*)d_in[3];
    const float* b    = (const float*)d_in[4];
    const float* gmm  = (const float*)d_in[5];
    const float* bet  = (const float*)d_in[6];

    const int N = in_sizes[0] / D;
    const int E = in_sizes[2];
    const int L = in_sizes[4] / D;
    const int NB = (N + 255) >> 8;   // buckets (dst>>8)

    // ---- carve workspace
    size_t off = 0;
    auto carve = [&](size_t bytes) -> void* {
        void* p = (char*)d_ws + off;
        off += (bytes + 255) & ~(size_t)255;
        return p;
    };
    float*    dinv       = (float*)carve((size_t)N * 4);
    int*      row_ptr    = (int*)  carve((size_t)(N + 1) * 4);
    int*      bucket_cnt = (int*)  carve(256 * 4);
    int*      bucket_base= (int*)  carve(257 * 4);
    int*      bucket_cur = (int*)  carve(256 * 4);
    int2*     csr_ew     = (int2*) carve((size_t)E * 8);
    unsigned* xlb        = (unsigned*)carve((size_t)N * 64 * 4);   // bf16-packed xl
    float*    hr         = (float*)carve((size_t)N * D * 4);
    float*    stats      = (float*)carve((size_t)L * 256 * 4);
    float*    ABbuf      = (float*)carve((size_t)L * 256 * 4);
    if (off > ws_size) return;

    int2* rec = (int2*)hr;           // pass-1 intermediate overlays hr (free until agg0)
    float* hout = (float*)d_out;

    // ---- build CSR (2-level bucketed counting sort) + normalization
    hipMemsetAsync(bucket_cnt, 0, 256 * 4, stream);
    hipMemsetAsync(stats, 0, (size_t)L * 256 * 4, stream);
    hist_kernel<<<1024, 256, 0, stream>>>(eidx + E, bucket_cnt, E, N);
    bucket_scan_kernel<<<1, 256, 0, stream>>>(bucket_cnt, bucket_base, bucket_cur, row_ptr, N);
    pass1_kernel<<<1024, 256, 0, stream>>>(eidx, ew, bucket_cur, rec, E, N);
    pass2_kernel<<<NB, 1024, 0, stream>>>(rec, bucket_base, csr_ew, row_ptr, dinv, N);
    scale_csr_kernel<<<1024, 256, 0, stream>>>(row_ptr, csr_ew, dinv, N);

    // ---- layers
    const float n_inv = 1.f / (float)N;
    for (int l = 0; l < L; l++) {
        const float* Hin = (l == 0) ? x : hr;
        const float* ABl = (l == 0) ? nullptr : ABbuf + (size_t)(l - 1) * 256;
        gemm128_kernel<<<1024, 256, 0, stream>>>(Hin, W + (size_t)l * D * D, ABl, xlb, N);
        agg_kernel<<<AGG_BLOCKS, 256, 0, stream>>>(xlb, row_ptr, csr_ew,
                                                   b + (size_t)l * D, hr, stats + (size_t)l * 256,
                                                   N, l > 0 ? 1 : 0);
        finalize_kernel<<<1, 128, 0, stream>>>(stats + (size_t)l * 256,
                                               gmm + (size_t)l * D, bet + (size_t)l * D,
                                               ABbuf + (size_t)l * 256, n_inv);
    }
    norm_relu_kernel<<<1024, 256, 0, stream>>>(hr, ABbuf + (size_t)(L - 1) * 256,
                                               hout, N * (D / 4));
}

// Round 7
// 504.575 us; speedup vs baseline: 4.2466x; 1.1376x over previous
//
#include <hip/hip_runtime.h>
#include <hip/hip_bf16.h>

#define D 128
#define AGG_BLOCKS 2048

typedef __attribute__((ext_vector_type(8))) short short8;
typedef __attribute__((ext_vector_type(4))) float f32x4;

// pack two f32 -> bf16 pair (RNE)
__device__ inline unsigned bf16pair(float x, float y) {
    unsigned xb = __float_as_uint(x), yb = __float_as_uint(y);
    xb = (xb + 0x7FFFu + ((xb >> 16) & 1u)) >> 16;
    yb = (yb + 0x7FFFu + ((yb >> 16) & 1u)) >> 16;
    return xb | (yb << 16);
}

// ---------------------------------------------------------------- pass 0: 256-bin histogram of dst>>8
__global__ void hist_kernel(const int* __restrict__ dst_idx,
                            int* __restrict__ bucket_cnt, int E, int N) {
    __shared__ int h[256];
    int t = threadIdx.x;
    h[t] = 0;
    __syncthreads();
    int e = blockIdx.x * blockDim.x + t;
    int stride = gridDim.x * blockDim.x;
    for (; e < E; e += stride) {
        int d = dst_idx[e];
        if ((unsigned)d < (unsigned)N) atomicAdd(&h[d >> 8], 1);
    }
    __syncthreads();
    if (h[t]) atomicAdd(&bucket_cnt[t], h[t]);
}

// ---------------------------------------------------------------- scan 256 buckets
__global__ void bucket_scan_kernel(const int* __restrict__ bucket_cnt,
                                   int* __restrict__ bucket_base,
                                   int* __restrict__ bucket_cursor,
                                   int* __restrict__ row_ptr, int N) {
    __shared__ int s[256];
    int t = threadIdx.x;
    s[t] = bucket_cnt[t];
    __syncthreads();
    for (int off = 1; off < 256; off <<= 1) {
        int v = (t >= off) ? s[t - off] : 0;
        __syncthreads();
        s[t] += v;
        __syncthreads();
    }
    int ex = t ? s[t - 1] : 0;
    bucket_base[t]   = ex;
    bucket_cursor[t] = ex;
    if (t == 255) { bucket_base[256] = s[255]; row_ptr[N] = s[255]; }
}

// ---------------------------------------------------------------- pass 1: chunked scatter into coarse buckets
#define CH 1024
__global__ void pass1_kernel(const int* __restrict__ idx,
                             const float* __restrict__ w,
                             int* __restrict__ bucket_cursor,
                             int2* __restrict__ rec, int E, int N) {
    __shared__ int h[256], bb[256], cur[256];
    const int* dst = idx + E;
    int t = threadIdx.x;
    int nchunks = (E + CH - 1) / CH;
    for (int c = blockIdx.x; c < nchunks; c += gridDim.x) {
        int lo = c * CH;
        int hi = lo + CH; if (hi > E) hi = E;
        h[t] = 0; cur[t] = 0;
        __syncthreads();
        for (int e = lo + t; e < hi; e += 256) {
            int d = dst[e];
            if ((unsigned)d < (unsigned)N) atomicAdd(&h[d >> 8], 1);
        }
        __syncthreads();
        if (h[t]) bb[t] = atomicAdd(&bucket_cursor[t], h[t]);
        __syncthreads();
        for (int e = lo + t; e < hi; e += 256) {
            int d = dst[e];
            if ((unsigned)d >= (unsigned)N) continue;
            int s = idx[e];
            int b = d >> 8;
            int r = atomicAdd(&cur[b], 1);
            rec[bb[b] + r] = make_int2((s & 0xFFFF) | ((d & 255) << 16),
                                       __float_as_int(w[e]));
        }
        __syncthreads();
    }
}

// ---------------------------------------------------------------- pass 2: per-bucket LDS counting sort -> CSR + row_ptr + dinv
__global__ void pass2_kernel(const int2* __restrict__ rec,
                             const int* __restrict__ bucket_base,
                             int2* __restrict__ csr,
                             int* __restrict__ row_ptr,
                             float* __restrict__ dinv, int N) {
    __shared__ int   hist[256], pref[256], cur[256];
    __shared__ float degs[256];
    int b = blockIdx.x;
    int t = threadIdx.x;
    int lo = bucket_base[b], hi = bucket_base[b + 1];
    if (t < 256) { hist[t] = 0; cur[t] = 0; degs[t] = 0.f; }
    __syncthreads();
    for (int e = lo + t; e < hi; e += blockDim.x)
        atomicAdd(&hist[(rec[e].x >> 16) & 255], 1);
    __syncthreads();
    for (int off = 1; off < 256; off <<= 1) {
        int v = 0;
        if (t < 256 && t >= off) v = hist[t - off];
        __syncthreads();
        if (t < 256) hist[t] += v;
        __syncthreads();
    }
    if (t < 256) {
        pref[t] = t ? hist[t - 1] : 0;
        int node = b * 256 + t;
        if (node < N) row_ptr[node] = lo + pref[t];
    }
    __syncthreads();
    for (int e = lo + t; e < hi; e += blockDim.x) {
        int2 rc = rec[e];
        int dl = (rc.x >> 16) & 255;
        int r = atomicAdd(&cur[dl], 1);
        csr[lo + pref[dl] + r] = rc;
        atomicAdd(&degs[dl], __int_as_float(rc.y));
    }
    __syncthreads();
    if (t < 256) {
        int node = b * 256 + t;
        if (node < N) {
            float dg = degs[t];
            dinv[node] = (dg > 0.f) ? rsqrtf(dg) : 0.f;
        }
    }
}

// ---------------------------------------------------------------- csr_w *= dinv[dst]*dinv[src]
__global__ void scale_csr_kernel(const int* __restrict__ row_ptr,
                                 int2* __restrict__ csr_ew,
                                 const float* __restrict__ dinv, int n) {
    int gwave = (blockIdx.x * blockDim.x + threadIdx.x) >> 6;
    int lane  = threadIdx.x & 63;
    int nwaves = (gridDim.x * blockDim.x) >> 6;
    for (int i = gwave; i < n; i += nwaves) {
        int beg = row_ptr[i], end = row_ptr[i + 1];
        float di = dinv[i];
        for (int e = beg + lane; e < end; e += 64) {
            int2 c = csr_ew[e];
            csr_ew[e].y = __float_as_int(__int_as_float(c.y) * di * dinv[c.x & 0xFFFF]);
        }
    }
}

// ---------------------------------------------------------------- MFMA GEMM: outb = bf16pack( act(H) @ Wl )
// 16x16x32 bf16 MFMA. W^T staged to LDS bf16 once, B-frags hoisted to VGPRs.
// A staged per 64-row tile with fused per-col relu(h*A+B) + bf16 cast.
__global__ __launch_bounds__(256, 2)
void gemm_mfma_kernel(const float* __restrict__ H, const float* __restrict__ Wl,
                      const float* __restrict__ AB,
                      unsigned* __restrict__ outb, int n) {
    __shared__ __align__(16) unsigned short Wt[128][136];  // W^T, padded
    __shared__ __align__(16) unsigned short As[64][136];   // A tile, padded
    int t = threadIdx.x;
    int w = t >> 6, l = t & 63;
    int col16 = l & 15, grp = l >> 4;

    // stage W^T as bf16 (one time)
    for (int i = t; i < 128 * 128; i += 256) {
        int k = i >> 7, j = i & 127;
        Wt[j][k] = (unsigned short)(bf16pair(Wl[i], 0.f) & 0xFFFFu);
    }
    __syncthreads();

    // hoist B-fragments: 8 n-tiles x 4 k-blocks
    short8 bfrag[8][4];
    #pragma unroll
    for (int tt = 0; tt < 8; tt++)
        #pragma unroll
        for (int kb = 0; kb < 4; kb++)
            bfrag[tt][kb] = *(const short8*)&Wt[tt * 16 + col16][kb * 32 + grp * 8];

    int ntiles = (n + 63) >> 6;
    for (int tile = blockIdx.x; tile < ntiles; tile += gridDim.x) {
        int base = tile << 6;
        __syncthreads();   // prior a-frag reads done before overwrite
        // stage A: 64 rows x 128 cols, fused act, bf16 pack
        for (int i = t; i < 64 * 32; i += 256) {
            int rr = i >> 5, cc = (i & 31) * 4;
            int row = base + rr;
            float4 v = make_float4(0.f, 0.f, 0.f, 0.f);
            if (row < n) v = *(const float4*)(H + (size_t)row * D + cc);
            if (AB) {
                float4 A = *(const float4*)(AB + cc);
                float4 B = *(const float4*)(AB + 128 + cc);
                v.x = fmaxf(fmaf(v.x, A.x, B.x), 0.f);
                v.y = fmaxf(fmaf(v.y, A.y, B.y), 0.f);
                v.z = fmaxf(fmaf(v.z, A.z, B.z), 0.f);
                v.w = fmaxf(fmaf(v.w, A.w, B.w), 0.f);
            }
            *(uint2*)&As[rr][cc] = make_uint2(bf16pair(v.x, v.y), bf16pair(v.z, v.w));
        }
        __syncthreads();

        // a-fragments for this wave's 16 rows
        int rowb = w * 16;
        short8 afrag[4];
        #pragma unroll
        for (int kb = 0; kb < 4; kb++)
            afrag[kb] = *(const short8*)&As[rowb + col16][kb * 32 + grp * 8];

        #pragma unroll
        for (int tt = 0; tt < 8; tt++) {
            f32x4 acc = {0.f, 0.f, 0.f, 0.f};
            #pragma unroll
            for (int kb = 0; kb < 4; kb++)
                acc = __builtin_amdgcn_mfma_f32_16x16x32_bf16(afrag[kb], bfrag[tt][kb], acc, 0, 0, 0);
            #pragma unroll
            for (int r = 0; r < 4; r++) {
                float v = acc[r];
                float nb = __shfl_xor(v, 1);
                if (!(l & 1)) {
                    int row = base + rowb + grp * 4 + r;
                    if (row < n)
                        outb[(size_t)row * 64 + tt * 8 + (col16 >> 1)] = bf16pair(v, nb);
                }
            }
        }
    }
}

// ---------------------------------------------------------------- pull aggregation: 2 edges per wave-gather
// lanes 0-31 = edge A (cols 4c..4c+3 via uint2), lanes 32-63 = edge B; combine via shfl.
__global__ void agg_kernel(const unsigned* __restrict__ xlb,
                           const int* __restrict__ row_ptr,
                           const int2* __restrict__ csr_ew,
                           const float* __restrict__ bvec,
                           float* __restrict__ hr,        // in(res)/out, f32
                           float* __restrict__ stats,     // [256]: sum | sumsq (atomic)
                           int n, int has_res) {
    int wave = threadIdx.x >> 6;
    int lane = threadIdx.x & 63;
    int half = lane >> 5;
    int cl   = lane & 31;          // col group: cols cl*4 .. cl*4+3
    int gwave = blockIdx.x * 4 + wave;
    int nwaves = gridDim.x * 4;

    float4 bb = *(const float4*)(bvec + cl * 4);
    float4 sA = make_float4(0.f, 0.f, 0.f, 0.f);
    float4 qA = make_float4(0.f, 0.f, 0.f, 0.f);

    for (int i = gwave; i < n; i += nwaves) {
        int beg = row_ptr[i], end = row_ptr[i + 1];
        float4 accA = make_float4(0.f, 0.f, 0.f, 0.f);
        float4 accB = make_float4(0.f, 0.f, 0.f, 0.f);
        int e = beg;
        // 16-edge batches: 8 gathers in flight, 2 edges each
        for (; e + 16 <= end; e += 16) {
            #pragma unroll
            for (int s = 0; s < 8; s++) {
                int2 c = csr_ew[e + 2 * s + half];
                uint2 g = *(const uint2*)(xlb + (size_t)(c.x & 0xFFFF) * 64 + cl * 2);
                float wv = __int_as_float(c.y);
                float4& ac = (s & 1) ? accB : accA;
                ac.x += wv * __uint_as_float(g.x << 16);
                ac.y += wv * __uint_as_float(g.x & 0xFFFF0000u);
                ac.z += wv * __uint_as_float(g.y << 16);
                ac.w += wv * __uint_as_float(g.y & 0xFFFF0000u);
            }
        }
        // 2-edge steps
        for (; e + 2 <= end; e += 2) {
            int2 c = csr_ew[e + half];
            uint2 g = *(const uint2*)(xlb + (size_t)(c.x & 0xFFFF) * 64 + cl * 2);
            float wv = __int_as_float(c.y);
            accA.x += wv * __uint_as_float(g.x << 16);
            accA.y += wv * __uint_as_float(g.x & 0xFFFF0000u);
            accA.z += wv * __uint_as_float(g.y << 16);
            accA.w += wv * __uint_as_float(g.y & 0xFFFF0000u);
        }
        // final odd edge (lower half only)
        if (e < end) {
            int2 c = csr_ew[e];
            uint2 g = *(const uint2*)(xlb + (size_t)(c.x & 0xFFFF) * 64 + cl * 2);
            float wv = (half == 0) ? __int_as_float(c.y) : 0.f;
            accA.x += wv * __uint_as_float(g.x << 16);
            accA.y += wv * __uint_as_float(g.x & 0xFFFF0000u);
            accA.z += wv * __uint_as_float(g.y << 16);
            accA.w += wv * __uint_as_float(g.y & 0xFFFF0000u);
        }
        float4 a;
        a.x = accA.x + accB.x; a.y = accA.y + accB.y;
        a.z = accA.z + accB.z; a.w = accA.w + accB.w;
        // combine halves
        a.x += __shfl_down(a.x, 32);
        a.y += __shfl_down(a.y, 32);
        a.z += __shfl_down(a.z, 32);
        a.w += __shfl_down(a.w, 32);
        if (half == 0) {
            a.x += bb.x; a.y += bb.y; a.z += bb.z; a.w += bb.w;
            if (has_res) {
                float4 rr = *(const float4*)(hr + (size_t)i * D + cl * 4);
                a.x += rr.x; a.y += rr.y; a.z += rr.z; a.w += rr.w;
            }
            *(float4*)(hr + (size_t)i * D + cl * 4) = a;
            sA.x += a.x; sA.y += a.y; sA.z += a.z; sA.w += a.w;
            qA.x += a.x * a.x; qA.y += a.y * a.y;
            qA.z += a.z * a.z; qA.w += a.w * a.w;
        }
    }

    __shared__ float redS[4][D];
    __shared__ float redQ[4][D];
    if (half == 0) {
        *(float4*)&redS[wave][cl * 4] = sA;
        *(float4*)&redQ[wave][cl * 4] = qA;
    }
    __syncthreads();
    int t = threadIdx.x;
    if (t < 128) {
        atomicAdd(&stats[t], redS[0][t] + redS[1][t] + redS[2][t] + redS[3][t]);
    } else {
        int c = t - 128;
        atomicAdd(&stats[t], redQ[0][c] + redQ[1][c] + redQ[2][c] + redQ[3][c]);
    }
}

// ---------------------------------------------------------------- finalize stats -> per-col scale/shift
__global__ void finalize_kernel(const float* __restrict__ stats,
                                const float* __restrict__ gamma_l,
                                const float* __restrict__ beta_l,
                                float* __restrict__ AB, float n_inv) {
    int t = threadIdx.x; // 128
    if (t < 128) {
        float mean = stats[t] * n_inv;
        float var  = stats[t + 128] * n_inv - mean * mean;
        var = fmaxf(var, 0.f);
        float rstd = rsqrtf(var + 1e-5f);
        float A = rstd * gamma_l[t];
        float B = beta_l[t] - mean * A;
        AB[t] = A;
        AB[128 + t] = B;
    }
}

// ---------------------------------------------------------------- normalize + relu (final layer only)
__global__ void norm_relu_kernel(const float* __restrict__ hr, const float* __restrict__ AB,
                                 float* __restrict__ hout, int total4) {
    int idx = blockIdx.x * blockDim.x + threadIdx.x;
    int stride = gridDim.x * blockDim.x;
    for (; idx < total4; idx += stride) {
        int c4 = (idx & 31) * 4;
        float4 v = ((const float4*)hr)[idx];
        float4 A = *(const float4*)(AB + c4);
        float4 B = *(const float4*)(AB + 128 + c4);
        v.x = fmaxf(fmaf(v.x, A.x, B.x), 0.f);
        v.y = fmaxf(fmaf(v.y, A.y, B.y), 0.f);
        v.z = fmaxf(fmaf(v.z, A.z, B.z), 0.f);
        v.w = fmaxf(fmaf(v.w, A.w, B.w), 0.f);
        ((float4*)hout)[idx] = v;
    }
}

// ================================================================ launch
extern "C" void kernel_launch(void* const* d_in, const int* in_sizes, int n_in,
                              void* d_out, int out_size, void* d_ws, size_t ws_size,
                              hipStream_t stream) {
    const float* x    = (const float*)d_in[0];
    const int*   eidx = (const int*)d_in[1];
    const float* ew   = (const float*)d_in[2];
    const float* W    = (const float*)d_in[3];
    const float* b    = (const float*)d_in[4];
    const float* gmm  = (const float*)d_in[5];
    const float* bet  = (const float*)d_in[6];

    const int N = in_sizes[0] / D;
    const int E = in_sizes[2];
    const int L = in_sizes[4] / D;
    const int NB = (N + 255) >> 8;

    size_t off = 0;
    auto carve = [&](size_t bytes) -> void* {
        void* p = (char*)d_ws + off;
        off += (bytes + 255) & ~(size_t)255;
        return p;
    };
    float*    dinv       = (float*)carve((size_t)N * 4);
    int*      row_ptr    = (int*)  carve((size_t)(N + 1) * 4);
    int*      bucket_cnt = (int*)  carve(256 * 4);
    int*      bucket_base= (int*)  carve(257 * 4);
    int*      bucket_cur = (int*)  carve(256 * 4);
    int2*     csr_ew     = (int2*) carve((size_t)E * 8);
    unsigned* xlb        = (unsigned*)carve((size_t)N * 64 * 4);
    float*    hr         = (float*)carve((size_t)N * D * 4);
    float*    stats      = (float*)carve((size_t)L * 256 * 4);
    float*    ABbuf      = (float*)carve((size_t)L * 256 * 4);
    if (off > ws_size) return;

    int2* rec = (int2*)hr;           // pass-1 intermediate overlays hr
    float* hout = (float*)d_out;

    hipMemsetAsync(bucket_cnt, 0, 256 * 4, stream);
    hipMemsetAsync(stats, 0, (size_t)L * 256 * 4, stream);
    hist_kernel<<<1024, 256, 0, stream>>>(eidx + E, bucket_cnt, E, N);
    bucket_scan_kernel<<<1, 256, 0, stream>>>(bucket_cnt, bucket_base, bucket_cur, row_ptr, N);
    pass1_kernel<<<1024, 256, 0, stream>>>(eidx, ew, bucket_cur, rec, E, N);
    pass2_kernel<<<NB, 1024, 0, stream>>>(rec, bucket_base, csr_ew, row_ptr, dinv, N);
    scale_csr_kernel<<<1024, 256, 0, stream>>>(row_ptr, csr_ew, dinv, N);

    const float n_inv = 1.f / (float)N;
    for (int l = 0; l < L; l++) {
        const float* Hin = (l == 0) ? x : hr;
        const float* ABl = (l == 0) ? nullptr : ABbuf + (size_t)(l - 1) * 256;
        gemm_mfma_kernel<<<512, 256, 0, stream>>>(Hin, W + (size_t)l * D * D, ABl, xlb, N);
        agg_kernel<<<AGG_BLOCKS, 256, 0, stream>>>(xlb, row_ptr, csr_ew,
                                                   b + (size_t)l * D, hr, stats + (size_t)l * 256,
                                                   N, l > 0 ? 1 : 0);
        finalize_kernel<<<1, 128, 0, stream>>>(stats + (size_t)l * 256,
                                               gmm + (size_t)l * D, bet + (size_t)l * D,
                                               ABbuf + (size_t)l * 256, n_inv);
    }
    norm_relu_kernel<<<1024, 256, 0, stream>>>(hr, ABbuf + (size_t)(L - 1) * 256,
                                               hout, N * (D / 4));
}

// Round 8
// 458.577 us; speedup vs baseline: 4.6725x; 1.1003x over previous
//
#include <hip/hip_runtime.h>
#include <hip/hip_bf16.h>

#define D 128
#define AGG_BLOCKS 2048

typedef __attribute__((ext_vector_type(8))) short short8;
typedef __attribute__((ext_vector_type(4))) float f32x4;

// pack two f32 -> bf16 pair (RNE)
__device__ inline unsigned bf16pair(float x, float y) {
    unsigned xb = __float_as_uint(x), yb = __float_as_uint(y);
    xb = (xb + 0x7FFFu + ((xb >> 16) & 1u)) >> 16;
    yb = (yb + 0x7FFFu + ((yb >> 16) & 1u)) >> 16;
    return xb | (yb << 16);
}

// ---------------------------------------------------------------- pass 0: 256-bin histogram of dst>>8
__global__ void hist_kernel(const int* __restrict__ dst_idx,
                            int* __restrict__ bucket_cnt, int E, int N) {
    __shared__ int h[256];
    int t = threadIdx.x;
    h[t] = 0;
    __syncthreads();
    int e = blockIdx.x * blockDim.x + t;
    int stride = gridDim.x * blockDim.x;
    for (; e < E; e += stride) {
        int d = dst_idx[e];
        if ((unsigned)d < (unsigned)N) atomicAdd(&h[d >> 8], 1);
    }
    __syncthreads();
    if (h[t]) atomicAdd(&bucket_cnt[t], h[t]);
}

// ---------------------------------------------------------------- scan 256 buckets
__global__ void bucket_scan_kernel(const int* __restrict__ bucket_cnt,
                                   int* __restrict__ bucket_base,
                                   int* __restrict__ bucket_cursor,
                                   int* __restrict__ row_ptr, int N) {
    __shared__ int s[256];
    int t = threadIdx.x;
    s[t] = bucket_cnt[t];
    __syncthreads();
    for (int off = 1; off < 256; off <<= 1) {
        int v = (t >= off) ? s[t - off] : 0;
        __syncthreads();
        s[t] += v;
        __syncthreads();
    }
    int ex = t ? s[t - 1] : 0;
    bucket_base[t]   = ex;
    bucket_cursor[t] = ex;
    if (t == 255) { bucket_base[256] = s[255]; row_ptr[N] = s[255]; }
}

// ---------------------------------------------------------------- pass 1: chunked scatter into coarse buckets
#define CH 1024
__global__ void pass1_kernel(const int* __restrict__ idx,
                             const float* __restrict__ w,
                             int* __restrict__ bucket_cursor,
                             int2* __restrict__ rec, int E, int N) {
    __shared__ int h[256], bb[256], cur[256];
    const int* dst = idx + E;
    int t = threadIdx.x;
    int nchunks = (E + CH - 1) / CH;
    for (int c = blockIdx.x; c < nchunks; c += gridDim.x) {
        int lo = c * CH;
        int hi = lo + CH; if (hi > E) hi = E;
        h[t] = 0; cur[t] = 0;
        __syncthreads();
        for (int e = lo + t; e < hi; e += 256) {
            int d = dst[e];
            if ((unsigned)d < (unsigned)N) atomicAdd(&h[d >> 8], 1);
        }
        __syncthreads();
        if (h[t]) bb[t] = atomicAdd(&bucket_cursor[t], h[t]);
        __syncthreads();
        for (int e = lo + t; e < hi; e += 256) {
            int d = dst[e];
            if ((unsigned)d >= (unsigned)N) continue;
            int s = idx[e];
            int b = d >> 8;
            int r = atomicAdd(&cur[b], 1);
            rec[bb[b] + r] = make_int2((s & 0xFFFF) | ((d & 255) << 16),
                                       __float_as_int(w[e]));
        }
        __syncthreads();
    }
}

// ---------------------------------------------------------------- pass 2: per-bucket LDS counting sort -> CSR (raw w) + row_ptr + dinv
__global__ void pass2_kernel(const int2* __restrict__ rec,
                             const int* __restrict__ bucket_base,
                             int2* __restrict__ csr,
                             int* __restrict__ row_ptr,
                             float* __restrict__ dinv, int N) {
    __shared__ int   hist[256], pref[256], cur[256];
    __shared__ float degs[256];
    int b = blockIdx.x;
    int t = threadIdx.x;
    int lo = bucket_base[b], hi = bucket_base[b + 1];
    if (t < 256) { hist[t] = 0; cur[t] = 0; degs[t] = 0.f; }
    __syncthreads();
    for (int e = lo + t; e < hi; e += blockDim.x)
        atomicAdd(&hist[(rec[e].x >> 16) & 255], 1);
    __syncthreads();
    for (int off = 1; off < 256; off <<= 1) {
        int v = 0;
        if (t < 256 && t >= off) v = hist[t - off];
        __syncthreads();
        if (t < 256) hist[t] += v;
        __syncthreads();
    }
    if (t < 256) {
        pref[t] = t ? hist[t - 1] : 0;
        int node = b * 256 + t;
        if (node < N) row_ptr[node] = lo + pref[t];
    }
    __syncthreads();
    for (int e = lo + t; e < hi; e += blockDim.x) {
        int2 rc = rec[e];
        int dl = (rc.x >> 16) & 255;
        int r = atomicAdd(&cur[dl], 1);
        csr[lo + pref[dl] + r] = rc;
        atomicAdd(&degs[dl], __int_as_float(rc.y));
    }
    __syncthreads();
    if (t < 256) {
        int node = b * 256 + t;
        if (node < N) {
            float dg = degs[t];
            dinv[node] = (dg > 0.f) ? rsqrtf(dg) : 0.f;
        }
    }
}

// ---------------------------------------------------------------- MFMA GEMM: outb = bf16pack( dinv[row] * act(H) @ Wl )
__global__ __launch_bounds__(256, 2)
void gemm_mfma_kernel(const float* __restrict__ H, const float* __restrict__ Wl,
                      const float* __restrict__ AB, const float* __restrict__ dinv,
                      unsigned* __restrict__ outb, int n) {
    __shared__ __align__(16) unsigned short Wt[128][136];  // W^T, padded
    __shared__ __align__(16) unsigned short As[64][136];   // A tile, padded
    int t = threadIdx.x;
    int w = t >> 6, l = t & 63;
    int col16 = l & 15, grp = l >> 4;

    // stage W^T as bf16 (one time)
    for (int i = t; i < 128 * 128; i += 256) {
        int k = i >> 7, j = i & 127;
        Wt[j][k] = (unsigned short)(bf16pair(Wl[i], 0.f) & 0xFFFFu);
    }
    __syncthreads();

    // hoist B-fragments: 8 n-tiles x 4 k-blocks
    short8 bfrag[8][4];
    #pragma unroll
    for (int tt = 0; tt < 8; tt++)
        #pragma unroll
        for (int kb = 0; kb < 4; kb++)
            bfrag[tt][kb] = *(const short8*)&Wt[tt * 16 + col16][kb * 32 + grp * 8];

    int ntiles = (n + 63) >> 6;
    for (int tile = blockIdx.x; tile < ntiles; tile += gridDim.x) {
        int base = tile << 6;
        __syncthreads();   // prior a-frag reads done before overwrite
        // stage A: 64 rows x 128 cols, fused act, bf16 pack
        for (int i = t; i < 64 * 32; i += 256) {
            int rr = i >> 5, cc = (i & 31) * 4;
            int row = base + rr;
            float4 v = make_float4(0.f, 0.f, 0.f, 0.f);
            if (row < n) v = *(const float4*)(H + (size_t)row * D + cc);
            if (AB) {
                float4 A = *(const float4*)(AB + cc);
                float4 B = *(const float4*)(AB + 128 + cc);
                v.x = fmaxf(fmaf(v.x, A.x, B.x), 0.f);
                v.y = fmaxf(fmaf(v.y, A.y, B.y), 0.f);
                v.z = fmaxf(fmaf(v.z, A.z, B.z), 0.f);
                v.w = fmaxf(fmaf(v.w, A.w, B.w), 0.f);
            }
            *(uint2*)&As[rr][cc] = make_uint2(bf16pair(v.x, v.y), bf16pair(v.z, v.w));
        }
        __syncthreads();

        // a-fragments for this wave's 16 rows
        int rowb = w * 16;
        short8 afrag[4];
        #pragma unroll
        for (int kb = 0; kb < 4; kb++)
            afrag[kb] = *(const short8*)&As[rowb + col16][kb * 32 + grp * 8];

        // per-output-row dinv (fold src-side GCN norm into the table)
        float dv[4];
        #pragma unroll
        for (int r = 0; r < 4; r++) {
            int row = base + rowb + grp * 4 + r;
            dv[r] = (row < n) ? dinv[row] : 0.f;
        }

        #pragma unroll
        for (int tt = 0; tt < 8; tt++) {
            f32x4 acc = {0.f, 0.f, 0.f, 0.f};
            #pragma unroll
            for (int kb = 0; kb < 4; kb++)
                acc = __builtin_amdgcn_mfma_f32_16x16x32_bf16(afrag[kb], bfrag[tt][kb], acc, 0, 0, 0);
            #pragma unroll
            for (int r = 0; r < 4; r++) {
                float v = acc[r] * dv[r];
                float nb = __shfl_xor(v, 1);
                if (!(l & 1)) {
                    int row = base + rowb + grp * 4 + r;
                    if (row < n)
                        outb[(size_t)row * 64 + tt * 8 + (col16 >> 1)] = bf16pair(v, nb);
                }
            }
        }
    }
}

// ---------------------------------------------------------------- pull aggregation + bias + residual + col-stats
// one wave per dst node; lane owns cols (2l,2l+1) as one packed uint; 8-deep gather pipeline.
// csr holds RAW weights; dst-side dinv applied once per row.
__global__ void agg_kernel(const unsigned* __restrict__ xlb,
                           const int* __restrict__ row_ptr,
                           const int2* __restrict__ csr_ew,
                           const float* __restrict__ dinv,
                           const float* __restrict__ bvec,
                           float* __restrict__ hr,        // in(res)/out, f32
                           float* __restrict__ stats,     // [256]: sum | sumsq (atomic)
                           int n, int has_res) {
    int wave = threadIdx.x >> 6;
    int lane = threadIdx.x & 63;
    int gwave = blockIdx.x * 4 + wave;
    int nwaves = gridDim.x * 4;

    float bb0 = bvec[lane * 2], bb1 = bvec[lane * 2 + 1];
    float s0 = 0.f, s1 = 0.f, q0 = 0.f, q1 = 0.f;

    for (int i = gwave; i < n; i += nwaves) {
        int beg = row_ptr[i], end = row_ptr[i + 1];
        float di = dinv[i];
        float pa0 = 0.f, pa1 = 0.f, pb0 = 0.f, pb1 = 0.f;
        float pc0 = 0.f, pc1 = 0.f, pd0 = 0.f, pd1 = 0.f;
        int e = beg;
        int e8 = beg + ((end - beg) & ~7);
        for (; e < e8; e += 8) {
            int2 c0 = csr_ew[e + 0], c1 = csr_ew[e + 1];
            int2 c2 = csr_ew[e + 2], c3 = csr_ew[e + 3];
            int2 c4 = csr_ew[e + 4], c5 = csr_ew[e + 5];
            int2 c6 = csr_ew[e + 6], c7 = csr_ew[e + 7];
            unsigned g0 = xlb[(size_t)(c0.x & 0xFFFF) * 64 + lane];
            unsigned g1 = xlb[(size_t)(c1.x & 0xFFFF) * 64 + lane];
            unsigned g2 = xlb[(size_t)(c2.x & 0xFFFF) * 64 + lane];
            unsigned g3 = xlb[(size_t)(c3.x & 0xFFFF) * 64 + lane];
            unsigned g4 = xlb[(size_t)(c4.x & 0xFFFF) * 64 + lane];
            unsigned g5 = xlb[(size_t)(c5.x & 0xFFFF) * 64 + lane];
            unsigned g6 = xlb[(size_t)(c6.x & 0xFFFF) * 64 + lane];
            unsigned g7 = xlb[(size_t)(c7.x & 0xFFFF) * 64 + lane];
            float w0 = __int_as_float(c0.y), w1 = __int_as_float(c1.y);
            float w2 = __int_as_float(c2.y), w3 = __int_as_float(c3.y);
            float w4 = __int_as_float(c4.y), w5 = __int_as_float(c5.y);
            float w6 = __int_as_float(c6.y), w7 = __int_as_float(c7.y);
            pa0 += w0 * __uint_as_float(g0 << 16); pa1 += w0 * __uint_as_float(g0 & 0xFFFF0000u);
            pb0 += w1 * __uint_as_float(g1 << 16); pb1 += w1 * __uint_as_float(g1 & 0xFFFF0000u);
            pc0 += w2 * __uint_as_float(g2 << 16); pc1 += w2 * __uint_as_float(g2 & 0xFFFF0000u);
            pd0 += w3 * __uint_as_float(g3 << 16); pd1 += w3 * __uint_as_float(g3 & 0xFFFF0000u);
            pa0 += w4 * __uint_as_float(g4 << 16); pa1 += w4 * __uint_as_float(g4 & 0xFFFF0000u);
            pb0 += w5 * __uint_as_float(g5 << 16); pb1 += w5 * __uint_as_float(g5 & 0xFFFF0000u);
            pc0 += w6 * __uint_as_float(g6 << 16); pc1 += w6 * __uint_as_float(g6 & 0xFFFF0000u);
            pd0 += w7 * __uint_as_float(g7 << 16); pd1 += w7 * __uint_as_float(g7 & 0xFFFF0000u);
        }
        for (; e < end; e++) {
            int2 c = csr_ew[e];
            float wv = __int_as_float(c.y);
            unsigned g = xlb[(size_t)(c.x & 0xFFFF) * 64 + lane];
            pa0 += wv * __uint_as_float(g << 16);
            pa1 += wv * __uint_as_float(g & 0xFFFF0000u);
        }
        float a0 = ((pa0 + pb0) + (pc0 + pd0)) * di + bb0;
        float a1 = ((pa1 + pb1) + (pc1 + pd1)) * di + bb1;
        if (has_res) {
            float2 rr = *(const float2*)(hr + (size_t)i * D + lane * 2);
            a0 += rr.x; a1 += rr.y;
        }
        *(float2*)(hr + (size_t)i * D + lane * 2) = make_float2(a0, a1);
        s0 += a0; s1 += a1;
        q0 += a0 * a0; q1 += a1 * a1;
    }

    __shared__ float redS[4][D];
    __shared__ float redQ[4][D];
    redS[wave][lane * 2] = s0; redS[wave][lane * 2 + 1] = s1;
    redQ[wave][lane * 2] = q0; redQ[wave][lane * 2 + 1] = q1;
    __syncthreads();
    int t = threadIdx.x;
    if (t < 128) {
        atomicAdd(&stats[t], redS[0][t] + redS[1][t] + redS[2][t] + redS[3][t]);
    } else {
        int c = t - 128;
        atomicAdd(&stats[t], redQ[0][c] + redQ[1][c] + redQ[2][c] + redQ[3][c]);
    }
}

// ---------------------------------------------------------------- finalize stats -> per-col scale/shift
__global__ void finalize_kernel(const float* __restrict__ stats,
                                const float* __restrict__ gamma_l,
                                const float* __restrict__ beta_l,
                                float* __restrict__ AB, float n_inv) {
    int t = threadIdx.x; // 128
    if (t < 128) {
        float mean = stats[t] * n_inv;
        float var  = stats[t + 128] * n_inv - mean * mean;
        var = fmaxf(var, 0.f);
        float rstd = rsqrtf(var + 1e-5f);
        float A = rstd * gamma_l[t];
        float B = beta_l[t] - mean * A;
        AB[t] = A;
        AB[128 + t] = B;
    }
}

// ---------------------------------------------------------------- normalize + relu (final layer only)
__global__ void norm_relu_kernel(const float* __restrict__ hr, const float* __restrict__ AB,
                                 float* __restrict__ hout, int total4) {
    int idx = blockIdx.x * blockDim.x + threadIdx.x;
    int stride = gridDim.x * blockDim.x;
    for (; idx < total4; idx += stride) {
        int c4 = (idx & 31) * 4;
        float4 v = ((const float4*)hr)[idx];
        float4 A = *(const float4*)(AB + c4);
        float4 B = *(const float4*)(AB + 128 + c4);
        v.x = fmaxf(fmaf(v.x, A.x, B.x), 0.f);
        v.y = fmaxf(fmaf(v.y, A.y, B.y), 0.f);
        v.z = fmaxf(fmaf(v.z, A.z, B.z), 0.f);
        v.w = fmaxf(fmaf(v.w, A.w, B.w), 0.f);
        ((float4*)hout)[idx] = v;
    }
}

// ================================================================ launch
extern "C" void kernel_launch(void* const* d_in, const int* in_sizes, int n_in,
                              void* d_out, int out_size, void* d_ws, size_t ws_size,
                              hipStream_t stream) {
    const float* x    = (const float*)d_in[0];
    const int*   eidx = (const int*)d_in[1];
    const float* ew   = (const float*)d_in[2];
    const float* W    = (const float*)d_in[3];
    const float* b    = (const float*)d_in[4];
    const float* gmm  = (const float*)d_in[5];
    const float* bet  = (const float*)d_in[6];

    const int N = in_sizes[0] / D;
    const int E = in_sizes[2];
    const int L = in_sizes[4] / D;
    const int NB = (N + 255) >> 8;

    size_t off = 0;
    auto carve = [&](size_t bytes) -> void* {
        void* p = (char*)d_ws + off;
        off += (bytes + 255) & ~(size_t)255;
        return p;
    };
    float*    dinv       = (float*)carve((size_t)N * 4);
    int*      row_ptr    = (int*)  carve((size_t)(N + 1) * 4);
    int*      bucket_cnt = (int*)  carve(256 * 4);
    int*      bucket_base= (int*)  carve(257 * 4);
    int*      bucket_cur = (int*)  carve(256 * 4);
    int2*     csr_ew     = (int2*) carve((size_t)E * 8);
    unsigned* xlb        = (unsigned*)carve((size_t)N * 64 * 4);
    float*    hr         = (float*)carve((size_t)N * D * 4);
    float*    stats      = (float*)carve((size_t)L * 256 * 4);
    float*    ABbuf      = (float*)carve((size_t)L * 256 * 4);
    if (off > ws_size) return;

    int2* rec = (int2*)hr;           // pass-1 intermediate overlays hr
    float* hout = (float*)d_out;

    hipMemsetAsync(bucket_cnt, 0, 256 * 4, stream);
    hipMemsetAsync(stats, 0, (size_t)L * 256 * 4, stream);
    hist_kernel<<<1024, 256, 0, stream>>>(eidx + E, bucket_cnt, E, N);
    bucket_scan_kernel<<<1, 256, 0, stream>>>(bucket_cnt, bucket_base, bucket_cur, row_ptr, N);
    pass1_kernel<<<1024, 256, 0, stream>>>(eidx, ew, bucket_cur, rec, E, N);
    pass2_kernel<<<NB, 1024, 0, stream>>>(rec, bucket_base, csr_ew, row_ptr, dinv, N);

    const float n_inv = 1.f / (float)N;
    for (int l = 0; l < L; l++) {
        const float* Hin = (l == 0) ? x : hr;
        const float* ABl = (l == 0) ? nullptr : ABbuf + (size_t)(l - 1) * 256;
        gemm_mfma_kernel<<<512, 256, 0, stream>>>(Hin, W + (size_t)l * D * D, ABl, dinv, xlb, N);
        agg_kernel<<<AGG_BLOCKS, 256, 0, stream>>>(xlb, row_ptr, csr_ew, dinv,
                                                   b + (size_t)l * D, hr, stats + (size_t)l * 256,
                                                   N, l > 0 ? 1 : 0);
        finalize_kernel<<<1, 128, 0, stream>>>(stats + (size_t)l * 256,
                                               gmm + (size_t)l * D, bet + (size_t)l * D,
                                               ABbuf + (size_t)l * 256, n_inv);
    }
    norm_relu_kernel<<<1024, 256, 0, stream>>>(hr, ABbuf + (size_t)(L - 1) * 256,
                                               hout, N * (D / 4));
}

// Round 9
// 455.343 us; speedup vs baseline: 4.7057x; 1.0071x over previous
//
#include <hip/hip_runtime.h>
#include <hip/hip_bf16.h>

#define D 128
#define AGG_BLOCKS 2048

typedef __attribute__((ext_vector_type(8))) short short8;
typedef __attribute__((ext_vector_type(4))) float f32x4;

// pack two f32 -> bf16 pair (RNE)
__device__ inline unsigned bf16pair(float x, float y) {
    unsigned xb = __float_as_uint(x), yb = __float_as_uint(y);
    xb = (xb + 0x7FFFu + ((xb >> 16) & 1u)) >> 16;
    yb = (yb + 0x7FFFu + ((yb >> 16) & 1u)) >> 16;
    return xb | (yb << 16);
}

// ---------------------------------------------------------------- pass 0: 256-bin histogram of dst>>8
__global__ void hist_kernel(const int* __restrict__ dst_idx,
                            int* __restrict__ bucket_cnt, int E, int N) {
    __shared__ int h[256];
    int t = threadIdx.x;
    h[t] = 0;
    __syncthreads();
    int e = blockIdx.x * blockDim.x + t;
    int stride = gridDim.x * blockDim.x;
    for (; e < E; e += stride) {
        int d = dst_idx[e];
        if ((unsigned)d < (unsigned)N) atomicAdd(&h[d >> 8], 1);
    }
    __syncthreads();
    if (h[t]) atomicAdd(&bucket_cnt[t], h[t]);
}

// ---------------------------------------------------------------- scan 256 buckets
__global__ void bucket_scan_kernel(const int* __restrict__ bucket_cnt,
                                   int* __restrict__ bucket_base,
                                   int* __restrict__ bucket_cursor,
                                   int* __restrict__ row_ptr, int N) {
    __shared__ int s[256];
    int t = threadIdx.x;
    s[t] = bucket_cnt[t];
    __syncthreads();
    for (int off = 1; off < 256; off <<= 1) {
        int v = (t >= off) ? s[t - off] : 0;
        __syncthreads();
        s[t] += v;
        __syncthreads();
    }
    int ex = t ? s[t - 1] : 0;
    bucket_base[t]   = ex;
    bucket_cursor[t] = ex;
    if (t == 255) { bucket_base[256] = s[255]; row_ptr[N] = s[255]; }
}

// ---------------------------------------------------------------- pass 1: chunked scatter into coarse buckets
#define CH 1024
__global__ void pass1_kernel(const int* __restrict__ idx,
                             const float* __restrict__ w,
                             int* __restrict__ bucket_cursor,
                             int2* __restrict__ rec, int E, int N) {
    __shared__ int h[256], bb[256], cur[256];
    const int* dst = idx + E;
    int t = threadIdx.x;
    int nchunks = (E + CH - 1) / CH;
    for (int c = blockIdx.x; c < nchunks; c += gridDim.x) {
        int lo = c * CH;
        int hi = lo + CH; if (hi > E) hi = E;
        h[t] = 0; cur[t] = 0;
        __syncthreads();
        for (int e = lo + t; e < hi; e += 256) {
            int d = dst[e];
            if ((unsigned)d < (unsigned)N) atomicAdd(&h[d >> 8], 1);
        }
        __syncthreads();
        if (h[t]) bb[t] = atomicAdd(&bucket_cursor[t], h[t]);
        __syncthreads();
        for (int e = lo + t; e < hi; e += 256) {
            int d = dst[e];
            if ((unsigned)d >= (unsigned)N) continue;
            int s = idx[e];
            int b = d >> 8;
            int r = atomicAdd(&cur[b], 1);
            rec[bb[b] + r] = make_int2((s & 0xFFFF) | ((d & 255) << 16),
                                       __float_as_int(w[e]));
        }
        __syncthreads();
    }
}

// ---------------------------------------------------------------- pass 2: per-bucket LDS counting sort -> CSR (raw w) + row_ptr + dinv
__global__ void pass2_kernel(const int2* __restrict__ rec,
                             const int* __restrict__ bucket_base,
                             int2* __restrict__ csr,
                             int* __restrict__ row_ptr,
                             float* __restrict__ dinv, int N) {
    __shared__ int   hist[256], pref[256], cur[256];
    __shared__ float degs[256];
    int b = blockIdx.x;
    int t = threadIdx.x;
    int lo = bucket_base[b], hi = bucket_base[b + 1];
    if (t < 256) { hist[t] = 0; cur[t] = 0; degs[t] = 0.f; }
    __syncthreads();
    for (int e = lo + t; e < hi; e += blockDim.x)
        atomicAdd(&hist[(rec[e].x >> 16) & 255], 1);
    __syncthreads();
    for (int off = 1; off < 256; off <<= 1) {
        int v = 0;
        if (t < 256 && t >= off) v = hist[t - off];
        __syncthreads();
        if (t < 256) hist[t] += v;
        __syncthreads();
    }
    if (t < 256) {
        pref[t] = t ? hist[t - 1] : 0;
        int node = b * 256 + t;
        if (node < N) row_ptr[node] = lo + pref[t];
    }
    __syncthreads();
    for (int e = lo + t; e < hi; e += blockDim.x) {
        int2 rc = rec[e];
        int dl = (rc.x >> 16) & 255;
        int r = atomicAdd(&cur[dl], 1);
        csr[lo + pref[dl] + r] = rc;
        atomicAdd(&degs[dl], __int_as_float(rc.y));
    }
    __syncthreads();
    if (t < 256) {
        int node = b * 256 + t;
        if (node < N) {
            float dg = degs[t];
            dinv[node] = (dg > 0.f) ? rsqrtf(dg) : 0.f;
        }
    }
}

// ---------------------------------------------------------------- MFMA GEMM: outb = bf16pack( dinv[row] * act(H) @ Wl )
__global__ __launch_bounds__(256, 2)
void gemm_mfma_kernel(const float* __restrict__ H, const float* __restrict__ Wl,
                      const float* __restrict__ AB, const float* __restrict__ dinv,
                      unsigned* __restrict__ outb, int n) {
    __shared__ __align__(16) unsigned short Wt[128][136];  // W^T, padded
    __shared__ __align__(16) unsigned short As[64][136];   // A tile, padded
    int t = threadIdx.x;
    int w = t >> 6, l = t & 63;
    int col16 = l & 15, grp = l >> 4;

    // stage W^T as bf16 (one time)
    for (int i = t; i < 128 * 128; i += 256) {
        int k = i >> 7, j = i & 127;
        Wt[j][k] = (unsigned short)(bf16pair(Wl[i], 0.f) & 0xFFFFu);
    }
    __syncthreads();

    // hoist B-fragments: 8 n-tiles x 4 k-blocks
    short8 bfrag[8][4];
    #pragma unroll
    for (int tt = 0; tt < 8; tt++)
        #pragma unroll
        for (int kb = 0; kb < 4; kb++)
            bfrag[tt][kb] = *(const short8*)&Wt[tt * 16 + col16][kb * 32 + grp * 8];

    int ntiles = (n + 63) >> 6;
    for (int tile = blockIdx.x; tile < ntiles; tile += gridDim.x) {
        int base = tile << 6;
        __syncthreads();   // prior a-frag reads done before overwrite
        // stage A: 64 rows x 128 cols, fused act, bf16 pack
        for (int i = t; i < 64 * 32; i += 256) {
            int rr = i >> 5, cc = (i & 31) * 4;
            int row = base + rr;
            float4 v = make_float4(0.f, 0.f, 0.f, 0.f);
            if (row < n) v = *(const float4*)(H + (size_t)row * D + cc);
            if (AB) {
                float4 A = *(const float4*)(AB + cc);
                float4 B = *(const float4*)(AB + 128 + cc);
                v.x = fmaxf(fmaf(v.x, A.x, B.x), 0.f);
                v.y = fmaxf(fmaf(v.y, A.y, B.y), 0.f);
                v.z = fmaxf(fmaf(v.z, A.z, B.z), 0.f);
                v.w = fmaxf(fmaf(v.w, A.w, B.w), 0.f);
            }
            *(uint2*)&As[rr][cc] = make_uint2(bf16pair(v.x, v.y), bf16pair(v.z, v.w));
        }
        __syncthreads();

        // a-fragments for this wave's 16 rows
        int rowb = w * 16;
        short8 afrag[4];
        #pragma unroll
        for (int kb = 0; kb < 4; kb++)
            afrag[kb] = *(const short8*)&As[rowb + col16][kb * 32 + grp * 8];

        // per-output-row dinv (fold src-side GCN norm into the table)
        float dv[4];
        #pragma unroll
        for (int r = 0; r < 4; r++) {
            int row = base + rowb + grp * 4 + r;
            dv[r] = (row < n) ? dinv[row] : 0.f;
        }

        #pragma unroll
        for (int tt = 0; tt < 8; tt++) {
            f32x4 acc = {0.f, 0.f, 0.f, 0.f};
            #pragma unroll
            for (int kb = 0; kb < 4; kb++)
                acc = __builtin_amdgcn_mfma_f32_16x16x32_bf16(afrag[kb], bfrag[tt][kb], acc, 0, 0, 0);
            #pragma unroll
            for (int r = 0; r < 4; r++) {
                float v = acc[r] * dv[r];
                float nb = __shfl_xor(v, 1);
                if (!(l & 1)) {
                    int row = base + rowb + grp * 4 + r;
                    if (row < n)
                        outb[(size_t)row * 64 + tt * 8 + (col16 >> 1)] = bf16pair(v, nb);
                }
            }
        }
    }
}

// ---------------------------------------------------------------- pull aggregation + bias + residual + col-stats
// one wave per dst node; lane owns cols (2l,2l+1) as one packed uint; 8-deep gather pipeline.
// csr holds RAW weights; dst-side dinv applied once per row.
__global__ void agg_kernel(const unsigned* __restrict__ xlb,
                           const int* __restrict__ row_ptr,
                           const int2* __restrict__ csr_ew,
                           const float* __restrict__ dinv,
                           const float* __restrict__ bvec,
                           float* __restrict__ hr,        // in(res)/out, f32
                           float* __restrict__ stats,     // [256]: sum | sumsq (atomic)
                           int n, int has_res) {
    int wave = threadIdx.x >> 6;
    int lane = threadIdx.x & 63;
    int gwave = blockIdx.x * 4 + wave;
    int nwaves = gridDim.x * 4;

    float bb0 = bvec[lane * 2], bb1 = bvec[lane * 2 + 1];
    float s0 = 0.f, s1 = 0.f, q0 = 0.f, q1 = 0.f;

    for (int i = gwave; i < n; i += nwaves) {
        int beg = row_ptr[i], end = row_ptr[i + 1];
        float di = dinv[i];
        float pa0 = 0.f, pa1 = 0.f, pb0 = 0.f, pb1 = 0.f;
        float pc0 = 0.f, pc1 = 0.f, pd0 = 0.f, pd1 = 0.f;
        int e = beg;
        int e8 = beg + ((end - beg) & ~7);
        for (; e < e8; e += 8) {
            int2 c0 = csr_ew[e + 0], c1 = csr_ew[e + 1];
            int2 c2 = csr_ew[e + 2], c3 = csr_ew[e + 3];
            int2 c4 = csr_ew[e + 4], c5 = csr_ew[e + 5];
            int2 c6 = csr_ew[e + 6], c7 = csr_ew[e + 7];
            unsigned g0 = xlb[(size_t)(c0.x & 0xFFFF) * 64 + lane];
            unsigned g1 = xlb[(size_t)(c1.x & 0xFFFF) * 64 + lane];
            unsigned g2 = xlb[(size_t)(c2.x & 0xFFFF) * 64 + lane];
            unsigned g3 = xlb[(size_t)(c3.x & 0xFFFF) * 64 + lane];
            unsigned g4 = xlb[(size_t)(c4.x & 0xFFFF) * 64 + lane];
            unsigned g5 = xlb[(size_t)(c5.x & 0xFFFF) * 64 + lane];
            unsigned g6 = xlb[(size_t)(c6.x & 0xFFFF) * 64 + lane];
            unsigned g7 = xlb[(size_t)(c7.x & 0xFFFF) * 64 + lane];
            float w0 = __int_as_float(c0.y), w1 = __int_as_float(c1.y);
            float w2 = __int_as_float(c2.y), w3 = __int_as_float(c3.y);
            float w4 = __int_as_float(c4.y), w5 = __int_as_float(c5.y);
            float w6 = __int_as_float(c6.y), w7 = __int_as_float(c7.y);
            pa0 += w0 * __uint_as_float(g0 << 16); pa1 += w0 * __uint_as_float(g0 & 0xFFFF0000u);
            pb0 += w1 * __uint_as_float(g1 << 16); pb1 += w1 * __uint_as_float(g1 & 0xFFFF0000u);
            pc0 += w2 * __uint_as_float(g2 << 16); pc1 += w2 * __uint_as_float(g2 & 0xFFFF0000u);
            pd0 += w3 * __uint_as_float(g3 << 16); pd1 += w3 * __uint_as_float(g3 & 0xFFFF0000u);
            pa0 += w4 * __uint_as_float(g4 << 16); pa1 += w4 * __uint_as_float(g4 & 0xFFFF0000u);
            pb0 += w5 * __uint_as_float(g5 << 16); pb1 += w5 * __uint_as_float(g5 & 0xFFFF0000u);
            pc0 += w6 * __uint_as_float(g6 << 16); pc1 += w6 * __uint_as_float(g6 & 0xFFFF0000u);
            pd0 += w7 * __uint_as_float(g7 << 16); pd1 += w7 * __uint_as_float(g7 & 0xFFFF0000u);
        }
        for (; e < end; e++) {
            int2 c = csr_ew[e];
            float wv = __int_as_float(c.y);
            unsigned g = xlb[(size_t)(c.x & 0xFFFF) * 64 + lane];
            pa0 += wv * __uint_as_float(g << 16);
            pa1 += wv * __uint_as_float(g & 0xFFFF0000u);
        }
        float a0 = ((pa0 + pb0) + (pc0 + pd0)) * di + bb0;
        float a1 = ((pa1 + pb1) + (pc1 + pd1)) * di + bb1;
        if (has_res) {
            float2 rr = *(const float2*)(hr + (size_t)i * D + lane * 2);
            a0 += rr.x; a1 += rr.y;
        }
        *(float2*)(hr + (size_t)i * D + lane * 2) = make_float2(a0, a1);
        s0 += a0; s1 += a1;
        q0 += a0 * a0; q1 += a1 * a1;
    }

    __shared__ float redS[4][D];
    __shared__ float redQ[4][D];
    redS[wave][lane * 2] = s0; redS[wave][lane * 2 + 1] = s1;
    redQ[wave][lane * 2] = q0; redQ[wave][lane * 2 + 1] = q1;
    __syncthreads();
    int t = threadIdx.x;
    if (t < 128) {
        atomicAdd(&stats[t], redS[0][t] + redS[1][t] + redS[2][t] + redS[3][t]);
    } else {
        int c = t - 128;
        atomicAdd(&stats[t], redQ[0][c] + redQ[1][c] + redQ[2][c] + redQ[3][c]);
    }
}

// ---------------------------------------------------------------- finalize stats -> per-col scale/shift
__global__ void finalize_kernel(const float* __restrict__ stats,
                                const float* __restrict__ gamma_l,
                                const float* __restrict__ beta_l,
                                float* __restrict__ AB, float n_inv) {
    int t = threadIdx.x; // 128
    if (t < 128) {
        float mean = stats[t] * n_inv;
        float var  = stats[t + 128] * n_inv - mean * mean;
        var = fmaxf(var, 0.f);
        float rstd = rsqrtf(var + 1e-5f);
        float A = rstd * gamma_l[t];
        float B = beta_l[t] - mean * A;
        AB[t] = A;
        AB[128 + t] = B;
    }
}

// ---------------------------------------------------------------- normalize + relu (final layer only)
__global__ void norm_relu_kernel(const float* __restrict__ hr, const float* __restrict__ AB,
                                 float* __restrict__ hout, int total4) {
    int idx = blockIdx.x * blockDim.x + threadIdx.x;
    int stride = gridDim.x * blockDim.x;
    for (; idx < total4; idx += stride) {
        int c4 = (idx & 31) * 4;
        float4 v = ((const float4*)hr)[idx];
        float4 A = *(const float4*)(AB + c4);
        float4 B = *(const float4*)(AB + 128 + c4);
        v.x = fmaxf(fmaf(v.x, A.x, B.x), 0.f);
        v.y = fmaxf(fmaf(v.y, A.y, B.y), 0.f);
        v.z = fmaxf(fmaf(v.z, A.z, B.z), 0.f);
        v.w = fmaxf(fmaf(v.w, A.w, B.w), 0.f);
        ((float4*)hout)[idx] = v;
    }
}

// ================================================================ launch
extern "C" void kernel_launch(void* const* d_in, const int* in_sizes, int n_in,
                              void* d_out, int out_size, void* d_ws, size_t ws_size,
                              hipStream_t stream) {
    const float* x    = (const float*)d_in[0];
    const int*   eidx = (const int*)d_in[1];
    const float* ew   = (const float*)d_in[2];
    const float* W    = (const float*)d_in[3];
    const float* b    = (const float*)d_in[4];
    const float* gmm  = (const float*)d_in[5];
    const float* bet  = (const float*)d_in[6];

    const int N = in_sizes[0] / D;
    const int E = in_sizes[2];
    const int L = in_sizes[4] / D;
    const int NB = (N + 255) >> 8;

    size_t off = 0;
    auto carve = [&](size_t bytes) -> void* {
        void* p = (char*)d_ws + off;
        off += (bytes + 255) & ~(size_t)255;
        return p;
    };
    float*    dinv       = (float*)carve((size_t)N * 4);
    int*      row_ptr    = (int*)  carve((size_t)(N + 1) * 4);
    int*      bucket_cnt = (int*)  carve(256 * 4);
    int*      bucket_base= (int*)  carve(257 * 4);
    int*      bucket_cur = (int*)  carve(256 * 4);
    int2*     csr_ew     = (int2*) carve((size_t)E * 8);
    unsigned* xlb        = (unsigned*)carve((size_t)N * 64 * 4);
    float*    hr         = (float*)carve((size_t)N * D * 4);
    float*    stats      = (float*)carve((size_t)L * 256 * 4);
    float*    ABbuf      = (float*)carve((size_t)L * 256 * 4);
    if (off > ws_size) return;

    int2* rec = (int2*)hr;           // pass-1 intermediate overlays hr
    float* hout = (float*)d_out;

    hipMemsetAsync(bucket_cnt, 0, 256 * 4, stream);
    hipMemsetAsync(stats, 0, (size_t)L * 256 * 4, stream);
    hist_kernel<<<1024, 256, 0, stream>>>(eidx + E, bucket_cnt, E, N);
    bucket_scan_kernel<<<1, 256, 0, stream>>>(bucket_cnt, bucket_base, bucket_cur, row_ptr, N);
    pass1_kernel<<<1024, 256, 0, stream>>>(eidx, ew, bucket_cur, rec, E, N);
    pass2_kernel<<<NB, 1024, 0, stream>>>(rec, bucket_base, csr_ew, row_ptr, dinv, N);

    const float n_inv = 1.f / (float)N;
    for (int l = 0; l < L; l++) {
        const float* Hin = (l == 0) ? x : hr;
        const float* ABl = (l == 0) ? nullptr : ABbuf + (size_t)(l - 1) * 256;
        gemm_mfma_kernel<<<512, 256, 0, stream>>>(Hin, W + (size_t)l * D * D, ABl, dinv, xlb, N);
        agg_kernel<<<AGG_BLOCKS, 256, 0, stream>>>(xlb, row_ptr, csr_ew, dinv,
                                                   b + (size_t)l * D, hr, stats + (size_t)l * 256,
                                                   N, l > 0 ? 1 : 0);
        finalize_kernel<<<1, 128, 0, stream>>>(stats + (size_t)l * 256,
                                               gmm + (size_t)l * D, bet + (size_t)l * D,
                                               ABbuf + (size_t)l * 256, n_inv);
    }
    norm_relu_kernel<<<1024, 256, 0, stream>>>(hr, ABbuf + (size_t)(L - 1) * 256,
                                               hout, N * (D / 4));
}

// Round 10
// 329.280 us; speedup vs baseline: 6.5073x; 1.3828x over previous
//
#include <hip/hip_runtime.h>
#include <hip/hip_bf16.h>

#define D 128
#define AGG_BLOCKS 2048
#define NSHARD 16

typedef __attribute__((ext_vector_type(8))) short short8;
typedef __attribute__((ext_vector_type(4))) float f32x4;

// pack two f32 -> bf16 pair (RNE)
__device__ inline unsigned bf16pair(float x, float y) {
    unsigned xb = __float_as_uint(x), yb = __float_as_uint(y);
    xb = (xb + 0x7FFFu + ((xb >> 16) & 1u)) >> 16;
    yb = (yb + 0x7FFFu + ((yb >> 16) & 1u)) >> 16;
    return xb | (yb << 16);
}

// ---------------------------------------------------------------- pass 0: 256-bin histogram of dst>>8
__global__ void hist_kernel(const int* __restrict__ dst_idx,
                            int* __restrict__ bucket_cnt, int E, int N) {
    __shared__ int h[256];
    int t = threadIdx.x;
    h[t] = 0;
    __syncthreads();
    int e = blockIdx.x * blockDim.x + t;
    int stride = gridDim.x * blockDim.x;
    for (; e < E; e += stride) {
        int d = dst_idx[e];
        if ((unsigned)d < (unsigned)N) atomicAdd(&h[d >> 8], 1);
    }
    __syncthreads();
    if (h[t]) atomicAdd(&bucket_cnt[t], h[t]);
}

// ---------------------------------------------------------------- scan 256 buckets
__global__ void bucket_scan_kernel(const int* __restrict__ bucket_cnt,
                                   int* __restrict__ bucket_base,
                                   int* __restrict__ bucket_cursor,
                                   int* __restrict__ row_ptr, int N) {
    __shared__ int s[256];
    int t = threadIdx.x;
    s[t] = bucket_cnt[t];
    __syncthreads();
    for (int off = 1; off < 256; off <<= 1) {
        int v = (t >= off) ? s[t - off] : 0;
        __syncthreads();
        s[t] += v;
        __syncthreads();
    }
    int ex = t ? s[t - 1] : 0;
    bucket_base[t]   = ex;
    bucket_cursor[t] = ex;
    if (t == 255) { bucket_base[256] = s[255]; row_ptr[N] = s[255]; }
}

// ---------------------------------------------------------------- pass 1: chunked scatter into coarse buckets
#define CH 1024
__global__ void pass1_kernel(const int* __restrict__ idx,
                             const float* __restrict__ w,
                             int* __restrict__ bucket_cursor,
                             int2* __restrict__ rec, int E, int N) {
    __shared__ int h[256], bb[256], cur[256];
    const int* dst = idx + E;
    int t = threadIdx.x;
    int nchunks = (E + CH - 1) / CH;
    for (int c = blockIdx.x; c < nchunks; c += gridDim.x) {
        int lo = c * CH;
        int hi = lo + CH; if (hi > E) hi = E;
        h[t] = 0; cur[t] = 0;
        __syncthreads();
        for (int e = lo + t; e < hi; e += 256) {
            int d = dst[e];
            if ((unsigned)d < (unsigned)N) atomicAdd(&h[d >> 8], 1);
        }
        __syncthreads();
        if (h[t]) bb[t] = atomicAdd(&bucket_cursor[t], h[t]);
        __syncthreads();
        for (int e = lo + t; e < hi; e += 256) {
            int d = dst[e];
            if ((unsigned)d >= (unsigned)N) continue;
            int s = idx[e];
            int b = d >> 8;
            int r = atomicAdd(&cur[b], 1);
            rec[bb[b] + r] = make_int2((s & 0xFFFF) | ((d & 255) << 16),
                                       __float_as_int(w[e]));
        }
        __syncthreads();
    }
}

// ---------------------------------------------------------------- pass 2: per-bucket LDS counting sort -> CSR (raw w) + row_ptr + dinv
__global__ void pass2_kernel(const int2* __restrict__ rec,
                             const int* __restrict__ bucket_base,
                             int2* __restrict__ csr,
                             int* __restrict__ row_ptr,
                             float* __restrict__ dinv, int N) {
    __shared__ int   hist[256], pref[256], cur[256];
    __shared__ float degs[256];
    int b = blockIdx.x;
    int t = threadIdx.x;
    int lo = bucket_base[b], hi = bucket_base[b + 1];
    if (t < 256) { hist[t] = 0; cur[t] = 0; degs[t] = 0.f; }
    __syncthreads();
    for (int e = lo + t; e < hi; e += blockDim.x)
        atomicAdd(&hist[(rec[e].x >> 16) & 255], 1);
    __syncthreads();
    for (int off = 1; off < 256; off <<= 1) {
        int v = 0;
        if (t < 256 && t >= off) v = hist[t - off];
        __syncthreads();
        if (t < 256) hist[t] += v;
        __syncthreads();
    }
    if (t < 256) {
        pref[t] = t ? hist[t - 1] : 0;
        int node = b * 256 + t;
        if (node < N) row_ptr[node] = lo + pref[t];
    }
    __syncthreads();
    for (int e = lo + t; e < hi; e += blockDim.x) {
        int2 rc = rec[e];
        int dl = (rc.x >> 16) & 255;
        int r = atomicAdd(&cur[dl], 1);
        csr[lo + pref[dl] + r] = rc;
        atomicAdd(&degs[dl], __int_as_float(rc.y));
    }
    __syncthreads();
    if (t < 256) {
        int node = b * 256 + t;
        if (node < N) {
            float dg = degs[t];
            dinv[node] = (dg > 0.f) ? rsqrtf(dg) : 0.f;
        }
    }
}

// ---------------------------------------------------------------- MFMA GEMM: outb = bf16pack( dinv[row] * act(H) @ Wl )
__global__ __launch_bounds__(256, 2)
void gemm_mfma_kernel(const float* __restrict__ H, const float* __restrict__ Wl,
                      const float* __restrict__ AB, const float* __restrict__ dinv,
                      unsigned* __restrict__ outb, int n) {
    __shared__ __align__(16) unsigned short Wt[128][136];  // W^T, padded
    __shared__ __align__(16) unsigned short As[64][136];   // A tile, padded
    int t = threadIdx.x;
    int w = t >> 6, l = t & 63;
    int col16 = l & 15, grp = l >> 4;

    // stage W^T as bf16 (one time)
    for (int i = t; i < 128 * 128; i += 256) {
        int k = i >> 7, j = i & 127;
        Wt[j][k] = (unsigned short)(bf16pair(Wl[i], 0.f) & 0xFFFFu);
    }
    __syncthreads();

    // hoist B-fragments: 8 n-tiles x 4 k-blocks
    short8 bfrag[8][4];
    #pragma unroll
    for (int tt = 0; tt < 8; tt++)
        #pragma unroll
        for (int kb = 0; kb < 4; kb++)
            bfrag[tt][kb] = *(const short8*)&Wt[tt * 16 + col16][kb * 32 + grp * 8];

    int ntiles = (n + 63) >> 6;
    for (int tile = blockIdx.x; tile < ntiles; tile += gridDim.x) {
        int base = tile << 6;
        __syncthreads();   // prior a-frag reads done before overwrite
        // stage A: 64 rows x 128 cols, fused act, bf16 pack
        for (int i = t; i < 64 * 32; i += 256) {
            int rr = i >> 5, cc = (i & 31) * 4;
            int row = base + rr;
            float4 v = make_float4(0.f, 0.f, 0.f, 0.f);
            if (row < n) v = *(const float4*)(H + (size_t)row * D + cc);
            if (AB) {
                float4 A = *(const float4*)(AB + cc);
                float4 B = *(const float4*)(AB + 128 + cc);
                v.x = fmaxf(fmaf(v.x, A.x, B.x), 0.f);
                v.y = fmaxf(fmaf(v.y, A.y, B.y), 0.f);
                v.z = fmaxf(fmaf(v.z, A.z, B.z), 0.f);
                v.w = fmaxf(fmaf(v.w, A.w, B.w), 0.f);
            }
            *(uint2*)&As[rr][cc] = make_uint2(bf16pair(v.x, v.y), bf16pair(v.z, v.w));
        }
        __syncthreads();

        // a-fragments for this wave's 16 rows
        int rowb = w * 16;
        short8 afrag[4];
        #pragma unroll
        for (int kb = 0; kb < 4; kb++)
            afrag[kb] = *(const short8*)&As[rowb + col16][kb * 32 + grp * 8];

        // per-output-row dinv (fold src-side GCN norm into the table)
        float dv[4];
        #pragma unroll
        for (int r = 0; r < 4; r++) {
            int row = base + rowb + grp * 4 + r;
            dv[r] = (row < n) ? dinv[row] : 0.f;
        }

        #pragma unroll
        for (int tt = 0; tt < 8; tt++) {
            f32x4 acc = {0.f, 0.f, 0.f, 0.f};
            #pragma unroll
            for (int kb = 0; kb < 4; kb++)
                acc = __builtin_amdgcn_mfma_f32_16x16x32_bf16(afrag[kb], bfrag[tt][kb], acc, 0, 0, 0);
            #pragma unroll
            for (int r = 0; r < 4; r++) {
                float v = acc[r] * dv[r];
                float nb = __shfl_xor(v, 1);
                if (!(l & 1)) {
                    int row = base + rowb + grp * 4 + r;
                    if (row < n)
                        outb[(size_t)row * 64 + tt * 8 + (col16 >> 1)] = bf16pair(v, nb);
                }
            }
        }
    }
}

// ---------------------------------------------------------------- pull aggregation + bias + residual + col-stats
// one wave per dst row chunk (contiguous rows -> sequential csr);
// csr batch k+1 prefetched before consuming gathers of batch k.
__global__ __launch_bounds__(256, 8)
void agg_kernel(const unsigned* __restrict__ xlb,
                const int* __restrict__ row_ptr,
                const int2* __restrict__ csr_ew,
                const float* __restrict__ dinv,
                const float* __restrict__ bvec,
                float* __restrict__ hr,        // in(res)/out, f32
                float* __restrict__ stats,     // [NSHARD][256]: sum | sumsq (atomic)
                int n, int has_res) {
    int wave = threadIdx.x >> 6;
    int lane = threadIdx.x & 63;
    int wid = blockIdx.x * 4 + wave;
    int nw = gridDim.x * 4;
    int chunk = (n + nw - 1) / nw;
    int r0 = wid * chunk;
    int r1 = r0 + chunk; if (r1 > n) r1 = n;

    float bb0 = bvec[lane * 2], bb1 = bvec[lane * 2 + 1];
    float s0 = 0.f, s1 = 0.f, q0 = 0.f, q1 = 0.f;

    for (int i = r0; i < r1; i++) {
        int beg = __builtin_amdgcn_readfirstlane(row_ptr[i]);
        int end = __builtin_amdgcn_readfirstlane(row_ptr[i + 1]);
        float di = __uint_as_float(
            (unsigned)__builtin_amdgcn_readfirstlane(__float_as_uint(dinv[i])));
        float pa0 = 0.f, pa1 = 0.f, pb0 = 0.f, pb1 = 0.f;
        float pc0 = 0.f, pc1 = 0.f, pd0 = 0.f, pd1 = 0.f;
        int nb = (end - beg) >> 3;           // full 8-edge batches
        int2 c0, c1, c2, c3, c4, c5, c6, c7;
        if (nb > 0) {
            c0 = csr_ew[beg + 0]; c1 = csr_ew[beg + 1];
            c2 = csr_ew[beg + 2]; c3 = csr_ew[beg + 3];
            c4 = csr_ew[beg + 4]; c5 = csr_ew[beg + 5];
            c6 = csr_ew[beg + 6]; c7 = csr_ew[beg + 7];
        }
        for (int k = 0; k < nb; k++) {
            // issue gathers for current batch
            unsigned g0 = xlb[(size_t)(c0.x & 0xFFFF) * 64 + lane];
            unsigned g1 = xlb[(size_t)(c1.x & 0xFFFF) * 64 + lane];
            unsigned g2 = xlb[(size_t)(c2.x & 0xFFFF) * 64 + lane];
            unsigned g3 = xlb[(size_t)(c3.x & 0xFFFF) * 64 + lane];
            unsigned g4 = xlb[(size_t)(c4.x & 0xFFFF) * 64 + lane];
            unsigned g5 = xlb[(size_t)(c5.x & 0xFFFF) * 64 + lane];
            unsigned g6 = xlb[(size_t)(c6.x & 0xFFFF) * 64 + lane];
            unsigned g7 = xlb[(size_t)(c7.x & 0xFFFF) * 64 + lane];
            float w0 = __int_as_float(c0.y), w1 = __int_as_float(c1.y);
            float w2 = __int_as_float(c2.y), w3 = __int_as_float(c3.y);
            float w4 = __int_as_float(c4.y), w5 = __int_as_float(c5.y);
            float w6 = __int_as_float(c6.y), w7 = __int_as_float(c7.y);
            // prefetch next batch's csr while gathers are in flight
            if (k + 1 < nb) {
                int eb = beg + (k + 1) * 8;
                c0 = csr_ew[eb + 0]; c1 = csr_ew[eb + 1];
                c2 = csr_ew[eb + 2]; c3 = csr_ew[eb + 3];
                c4 = csr_ew[eb + 4]; c5 = csr_ew[eb + 5];
                c6 = csr_ew[eb + 6]; c7 = csr_ew[eb + 7];
            }
            // consume gathers
            pa0 += w0 * __uint_as_float(g0 << 16); pa1 += w0 * __uint_as_float(g0 & 0xFFFF0000u);
            pb0 += w1 * __uint_as_float(g1 << 16); pb1 += w1 * __uint_as_float(g1 & 0xFFFF0000u);
            pc0 += w2 * __uint_as_float(g2 << 16); pc1 += w2 * __uint_as_float(g2 & 0xFFFF0000u);
            pd0 += w3 * __uint_as_float(g3 << 16); pd1 += w3 * __uint_as_float(g3 & 0xFFFF0000u);
            pa0 += w4 * __uint_as_float(g4 << 16); pa1 += w4 * __uint_as_float(g4 & 0xFFFF0000u);
            pb0 += w5 * __uint_as_float(g5 << 16); pb1 += w5 * __uint_as_float(g5 & 0xFFFF0000u);
            pc0 += w6 * __uint_as_float(g6 << 16); pc1 += w6 * __uint_as_float(g6 & 0xFFFF0000u);
            pd0 += w7 * __uint_as_float(g7 << 16); pd1 += w7 * __uint_as_float(g7 & 0xFFFF0000u);
        }
        for (int e = beg + nb * 8; e < end; e++) {
            int2 c = csr_ew[e];
            float wv = __int_as_float(c.y);
            unsigned g = xlb[(size_t)(c.x & 0xFFFF) * 64 + lane];
            pa0 += wv * __uint_as_float(g << 16);
            pa1 += wv * __uint_as_float(g & 0xFFFF0000u);
        }
        float a0 = ((pa0 + pb0) + (pc0 + pd0)) * di + bb0;
        float a1 = ((pa1 + pb1) + (pc1 + pd1)) * di + bb1;
        if (has_res) {
            float2 rr = *(const float2*)(hr + (size_t)i * D + lane * 2);
            a0 += rr.x; a1 += rr.y;
        }
        *(float2*)(hr + (size_t)i * D + lane * 2) = make_float2(a0, a1);
        s0 += a0; s1 += a1;
        q0 += a0 * a0; q1 += a1 * a1;
    }

    __shared__ float redS[4][D];
    __shared__ float redQ[4][D];
    redS[wave][lane * 2] = s0; redS[wave][lane * 2 + 1] = s1;
    redQ[wave][lane * 2] = q0; redQ[wave][lane * 2 + 1] = q1;
    __syncthreads();
    int t = threadIdx.x;
    float* sh = stats + (size_t)(blockIdx.x & (NSHARD - 1)) * 256;
    if (t < 128) {
        atomicAdd(&sh[t], redS[0][t] + redS[1][t] + redS[2][t] + redS[3][t]);
    } else {
        int c = t - 128;
        atomicAdd(&sh[128 + c], redQ[0][c] + redQ[1][c] + redQ[2][c] + redQ[3][c]);
    }
}

// ---------------------------------------------------------------- finalize stats (sum shards) -> per-col scale/shift
__global__ void finalize_kernel(const float* __restrict__ stats,
                                const float* __restrict__ gamma_l,
                                const float* __restrict__ beta_l,
                                float* __restrict__ AB, float n_inv) {
    int t = threadIdx.x; // 128
    if (t < 128) {
        float sum = 0.f, sq = 0.f;
        #pragma unroll
        for (int s = 0; s < NSHARD; s++) {
            sum += stats[s * 256 + t];
            sq  += stats[s * 256 + 128 + t];
        }
        float mean = sum * n_inv;
        float var  = sq * n_inv - mean * mean;
        var = fmaxf(var, 0.f);
        float rstd = rsqrtf(var + 1e-5f);
        float A = rstd * gamma_l[t];
        float B = beta_l[t] - mean * A;
        AB[t] = A;
        AB[128 + t] = B;
    }
}

// ---------------------------------------------------------------- normalize + relu (final layer only)
__global__ void norm_relu_kernel(const float* __restrict__ hr, const float* __restrict__ AB,
                                 float* __restrict__ hout, int total4) {
    int idx = blockIdx.x * blockDim.x + threadIdx.x;
    int stride = gridDim.x * blockDim.x;
    for (; idx < total4; idx += stride) {
        int c4 = (idx & 31) * 4;
        float4 v = ((const float4*)hr)[idx];
        float4 A = *(const float4*)(AB + c4);
        float4 B = *(const float4*)(AB + 128 + c4);
        v.x = fmaxf(fmaf(v.x, A.x, B.x), 0.f);
        v.y = fmaxf(fmaf(v.y, A.y, B.y), 0.f);
        v.z = fmaxf(fmaf(v.z, A.z, B.z), 0.f);
        v.w = fmaxf(fmaf(v.w, A.w, B.w), 0.f);
        ((float4*)hout)[idx] = v;
    }
}

// ================================================================ launch
extern "C" void kernel_launch(void* const* d_in, const int* in_sizes, int n_in,
                              void* d_out, int out_size, void* d_ws, size_t ws_size,
                              hipStream_t stream) {
    const float* x    = (const float*)d_in[0];
    const int*   eidx = (const int*)d_in[1];
    const float* ew   = (const float*)d_in[2];
    const float* W    = (const float*)d_in[3];
    const float* b    = (const float*)d_in[4];
    const float* gmm  = (const float*)d_in[5];
    const float* bet  = (const float*)d_in[6];

    const int N = in_sizes[0] / D;
    const int E = in_sizes[2];
    const int L = in_sizes[4] / D;
    const int NB = (N + 255) >> 8;

    size_t off = 0;
    auto carve = [&](size_t bytes) -> void* {
        void* p = (char*)d_ws + off;
        off += (bytes + 255) & ~(size_t)255;
        return p;
    };
    float*    dinv       = (float*)carve((size_t)N * 4);
    int*      row_ptr    = (int*)  carve((size_t)(N + 1) * 4);
    int*      bucket_cnt = (int*)  carve(256 * 4);
    int*      bucket_base= (int*)  carve(257 * 4);
    int*      bucket_cur = (int*)  carve(256 * 4);
    int2*     csr_ew     = (int2*) carve((size_t)E * 8);
    unsigned* xlb        = (unsigned*)carve((size_t)N * 64 * 4);
    float*    hr         = (float*)carve((size_t)N * D * 4);
    float*    stats      = (float*)carve((size_t)L * NSHARD * 256 * 4);
    float*    ABbuf      = (float*)carve((size_t)L * 256 * 4);
    if (off > ws_size) return;

    int2* rec = (int2*)hr;           // pass-1 intermediate overlays hr
    float* hout = (float*)d_out;

    hipMemsetAsync(bucket_cnt, 0, 256 * 4, stream);
    hipMemsetAsync(stats, 0, (size_t)L * NSHARD * 256 * 4, stream);
    hist_kernel<<<1024, 256, 0, stream>>>(eidx + E, bucket_cnt, E, N);
    bucket_scan_kernel<<<1, 256, 0, stream>>>(bucket_cnt, bucket_base, bucket_cur, row_ptr, N);
    pass1_kernel<<<1024, 256, 0, stream>>>(eidx, ew, bucket_cur, rec, E, N);
    pass2_kernel<<<NB, 1024, 0, stream>>>(rec, bucket_base, csr_ew, row_ptr, dinv, N);

    const float n_inv = 1.f / (float)N;
    for (int l = 0; l < L; l++) {
        const float* Hin = (l == 0) ? x : hr;
        const float* ABl = (l == 0) ? nullptr : ABbuf + (size_t)(l - 1) * 256;
        gemm_mfma_kernel<<<512, 256, 0, stream>>>(Hin, W + (size_t)l * D * D, ABl, dinv, xlb, N);
        agg_kernel<<<AGG_BLOCKS, 256, 0, stream>>>(xlb, row_ptr, csr_ew, dinv,
                                                   b + (size_t)l * D, hr,
                                                   stats + (size_t)l * NSHARD * 256,
                                                   N, l > 0 ? 1 : 0);
        finalize_kernel<<<1, 128, 0, stream>>>(stats + (size_t)l * NSHARD * 256,
                                               gmm + (size_t)l * D, bet + (size_t)l * D,
                                               ABbuf + (size_t)l * 256, n_inv);
    }
    norm_relu_kernel<<<1024, 256, 0, stream>>>(hr, ABbuf + (size_t)(L - 1) * 256,
                                               hout, N * (D / 4));
}